// Round 3
// baseline (4609.213 us; speedup 1.0000x reference)
//
#include <hip/hip_runtime.h>
#include <float.h>
#include <math.h>
#include <stdint.h>

#define LT 1360
#define BB 4
#define DM 512
#define NHH 8

// ---------------- block helpers (sizes 1024,256,64,16; starts 0,1024,1280,1344)
__device__ __forceinline__ void blk_info(int i, int& bi, int& st, int& n){
    if (i < 1024){ bi = 0; st = 0;    n = 1024; }
    else if (i < 1280){ bi = 1; st = 1024; n = 256; }
    else if (i < 1344){ bi = 2; st = 1280; n = 64; }
    else { bi = 3; st = 1344; n = 16; }
}

// ---------------- temporal allowed-index lists: TIDX[i*12+t], TCNT[i]
__global__ __launch_bounds__(256)
void build_tidx(int* __restrict__ idx, int* __restrict__ cnt){
    int i = blockIdx.x * 256 + threadIdx.x;
    if (i >= LT) return;
    int bi, st, n; blk_info(i, bi, st, n);
    int c = 0; int* row = idx + i * 12;
    int lo = (i - 2 > st) ? i - 2 : st;
    int hi = (i + 2 < st + n - 1) ? i + 2 : st + n - 1;
    for (int j = lo; j <= hi; j++) row[c++] = j;       // inner window (incl self)
    if (bi < 3) row[c++] = st + n + (i - st) / 4;      // parent in next (coarser) block
    if (bi > 0){                                        // 4 children in previous block
        int stc = st - n * 4;
        int base = stc + (i - st) * 4;
        for (int t = 0; t < 4; t++) row[c++] = base + t;
    }
    cnt[i] = c;
}

// ---------------- conv weight repack: wr[(k*512+ii)*512 + o] = cw[o][ii][k]
__global__ __launch_bounds__(256)
void repack_w(const float* __restrict__ cw, float* __restrict__ wr){
    int idx = blockIdx.x * 256 + threadIdx.x;   // 2048*512
    int p = idx >> 9;          // k*512+ii
    int o = idx & 511;
    int k = p >> 9;
    int ii = p & 511;
    wr[idx] = cw[((size_t)o * 512 + ii) * 4 + k];
}

// ---------------- generic fp32 GEMM, 64x64 tile, BK=16, 256 thr, 4x4/thread
__global__ __launch_bounds__(256)
void gemm_f32(const float* __restrict__ A, const float* __restrict__ Bm,
              const float* __restrict__ bias, const float* __restrict__ Rres,
              float* __restrict__ C, int M, int N, int K,
              int mpb, int orpb, int ooff, int act)
{
    __shared__ float As[16][65];   // +1 pad: breaks 4-way conflict on scalar stores
    __shared__ float Bs[16][68];   // +4 pad: float4-aligned, de-conflicts b128 stores
    int tid = threadIdx.x;
    int tx = tid & 15, ty = tid >> 4;
    int gm = blockIdx.y << 6, gn = blockIdx.x << 6;
    int lm = tid >> 2, lk4 = (tid & 3) << 2;
    int bk = tid >> 4, bn4 = (tid & 15) << 2;
    float acc[4][4] = {{0.f,0.f,0.f,0.f},{0.f,0.f,0.f,0.f},{0.f,0.f,0.f,0.f},{0.f,0.f,0.f,0.f}};
    for (int k0 = 0; k0 < K; k0 += 16){
        float4 av = *(const float4*)(A + (size_t)(gm + lm) * K + k0 + lk4);
        As[lk4+0][lm] = av.x; As[lk4+1][lm] = av.y;
        As[lk4+2][lm] = av.z; As[lk4+3][lm] = av.w;
        float4 bv = *(const float4*)(Bm + (size_t)(k0 + bk) * N + gn + bn4);
        *(float4*)&Bs[bk][bn4] = bv;
        __syncthreads();
        #pragma unroll
        for (int kk = 0; kk < 16; kk++){
            float ar[4], br[4];
            #pragma unroll
            for (int i = 0; i < 4; i++) ar[i] = As[kk][(ty<<2)+i];
            #pragma unroll
            for (int j = 0; j < 4; j++) br[j] = Bs[kk][(tx<<2)+j];
            #pragma unroll
            for (int i = 0; i < 4; i++)
                #pragma unroll
                for (int j = 0; j < 4; j++)
                    acc[i][j] = fmaf(ar[i], br[j], acc[i][j]);
        }
        __syncthreads();
    }
    const float cscale = 0.9999950000375f;   // 1/sqrt(1+1e-5)
    #pragma unroll
    for (int i = 0; i < 4; i++){
        int row = gm + (ty<<2) + i;
        int orow = (row / mpb) * orpb + ooff + (row % mpb);
        #pragma unroll
        for (int j = 0; j < 4; j++){
            int col = gn + (tx<<2) + j;
            float v = acc[i][j];
            if (bias) v += bias[col];
            if (Rres) v += Rres[(size_t)orow * N + col];
            if (act == 1){ v *= cscale; v = (v > 0.f) ? v : expm1f(v); }
            else if (act == 2){ v = fmaxf(v, 0.f); }
            C[(size_t)orow * N + col] = v;
        }
    }
}

// ---------------- concat conv pyramids
__global__ __launch_bounds__(256)
void pcat_copy(const float* __restrict__ C1, const float* __restrict__ C2,
               const float* __restrict__ C3, float* __restrict__ PC){
    int idx = blockIdx.x * 256 + threadIdx.x;   // 4*336*512
    int d = idx & 511;
    int r = (idx >> 9) % 336;
    int b = idx / (336 * 512);
    float v;
    if (r < 256)       v = C1[(((size_t)b * 256 + r) << 9) + d];
    else if (r < 320)  v = C2[(((size_t)b * 64 + (r - 256)) << 9) + d];
    else               v = C3[(((size_t)b * 16 + (r - 320)) << 9) + d];
    PC[idx] = v;
}

// ---------------- copy x_enc (B,1024,512) into rows [0,1024) of (B,1360,512)
__global__ __launch_bounds__(256)
void xenc_copy(const float* __restrict__ xe, float* __restrict__ dst){
    int idx = blockIdx.x * 256 + threadIdx.x;   // 4*1024*512
    int d = idx & 511;
    int l = (idx >> 9) & 1023;
    int b = idx >> 19;
    dst[(((size_t)b * LT + l) << 9) + d] = xe[idx];
}

// ---------------- LayerNorm over 512, wave per row
__global__ __launch_bounds__(256)
void ln_kernel(const float* __restrict__ in, const float* __restrict__ g,
               const float* __restrict__ bta, float* __restrict__ out, float eps){
    int wid = threadIdx.x >> 6, lane = threadIdx.x & 63;
    int row = blockIdx.x * 4 + wid;
    const float* p = in + ((size_t)row << 9);
    float vals[8]; float s = 0.f, s2 = 0.f;
    #pragma unroll
    for (int t = 0; t < 8; t++){
        float v = p[lane + t * 64]; vals[t] = v; s += v; s2 += v * v;
    }
    #pragma unroll
    for (int off = 32; off; off >>= 1){
        s  += __shfl_xor(s,  off, 64);
        s2 += __shfl_xor(s2, off, 64);
    }
    float mu = s * (1.f / 512.f);
    float var = s2 * (1.f / 512.f) - mu * mu;
    float r = rsqrtf(var + eps);
    float* q = out + ((size_t)row << 9);
    #pragma unroll
    for (int t = 0; t < 8; t++){
        int c = lane + t * 64;
        q[c] = (vals[t] - mu) * r * g[c] + bta[c];
    }
}

// ---------------- row L2-normalize, wave per row
__global__ __launch_bounds__(256)
void rownorm_kernel(const float* __restrict__ in, float* __restrict__ out){
    int wid = threadIdx.x >> 6, lane = threadIdx.x & 63;
    int row = blockIdx.x * 4 + wid;
    const float* p = in + ((size_t)row << 9);
    float vals[8]; float s2 = 0.f;
    #pragma unroll
    for (int t = 0; t < 8; t++){
        float v = p[lane + t * 64]; vals[t] = v; s2 += v * v;
    }
    #pragma unroll
    for (int off = 32; off; off >>= 1) s2 += __shfl_xor(s2, off, 64);
    float inv = 1.f / fmaxf(sqrtf(s2), 1e-8f);
    float* q = out + ((size_t)row << 9);
    #pragma unroll
    for (int t = 0; t < 8; t++) q[lane + t * 64] = vals[t] * inv;
}

// ---------------- semantic top-k per row: radix select (histogram on monotone key)
__device__ __forceinline__ uint32_t mono_key(float v){
    uint32_t b = __float_as_uint(v);
    return b ^ ((b & 0x80000000u) ? 0xFFFFFFFFu : 0x80000000u);
}

__global__ __launch_bounds__(256)
void topk_kernel(const float* __restrict__ XNp, uint8_t* __restrict__ SM){
    __shared__ float sim[1024];
    __shared__ float qrow[512];
    __shared__ uint32_t hist[256];
    __shared__ int lidx[1024];
    __shared__ int scal[3];          // 0: cutoff bin B, 1: cnt_gt(B), 2: list count
    int r = blockIdx.x;              // 0..B*LT-1
    int b = r / LT, i = r % LT;
    int bi, st, n; blk_info(i, bi, st, n);
    int tid = threadIdx.x;
    const float* xr = XNp + (((size_t)b * LT + i) << 9);
    for (int d = tid; d < 512; d += 256) qrow[d] = xr[d];
    hist[tid] = 0;
    if (tid == 0) scal[2] = 0;
    __syncthreads();
    // sim + 8-bit histogram of monotone key
    for (int j = tid; j < n; j += 256){
        const float4* xc = (const float4*)(XNp + (((size_t)b * LT + st + j) << 9));
        float acc = 0.f;
        #pragma unroll 4
        for (int d = 0; d < 128; d++){
            float4 x4 = xc[d];
            acc += qrow[4*d+0]*x4.x + qrow[4*d+1]*x4.y + qrow[4*d+2]*x4.z + qrow[4*d+3]*x4.w;
        }
        sim[j] = acc;
        atomicAdd(&hist[mono_key(acc) >> 24], 1u);
    }
    __syncthreads();
    // suffix sum: hist[t] <- sum_{b>=t} hist[b]   (Hillis-Steele, read/sync/write/sync)
    #pragma unroll
    for (int off = 1; off < 256; off <<= 1){
        uint32_t add = (tid + off < 256) ? hist[tid + off] : 0u;
        __syncthreads();
        hist[tid] += add;
        __syncthreads();
    }
    int k = (n < 32) ? n : 32;
    uint32_t ge = hist[tid];
    uint32_t gt = (tid < 255) ? hist[tid + 1] : 0u;
    if (ge >= (uint32_t)k && gt < (uint32_t)k){ scal[0] = tid; scal[1] = (int)gt; }
    __syncthreads();
    int Bcut = scal[0], C1 = scal[1];
    int R = k - C1;                       // boundary-bin slots still to fill (>=1)
    uint8_t* mrow = SM + ((size_t)b * LT + i) * LT + st;
    for (int j = tid; j < n; j += 256){
        int bin = (int)(mono_key(sim[j]) >> 24);
        if (bin > Bcut) mrow[j] = 1;
        else if (bin == Bcut){ int p = atomicAdd(&scal[2], 1); lidx[p] = j; }
    }
    __syncthreads();
    int cb = scal[2];
    // refine boundary bin: pick R best by (value desc, index asc) — single wave
    for (int it = 0; it < R; it++){
        if (tid < 64){
            float bv = -FLT_MAX; int bj = 1 << 30;
            for (int p = tid; p < cb; p += 64){
                int j = lidx[p]; float v = sim[j];
                if (v > bv || (v == bv && j < bj)){ bv = v; bj = j; }
            }
            #pragma unroll
            for (int off = 32; off; off >>= 1){
                float ov = __shfl_xor(bv, off, 64);
                int   oj = __shfl_xor(bj, off, 64);
                if (ov > bv || (ov == bv && oj < bj)){ bv = ov; bj = oj; }
            }
            if (tid == 0){ mrow[bj] = 1; sim[bj] = -FLT_MAX; }
        }
        __syncthreads();
    }
}

// ---------------- sparse attention via index lists (temporal), wave per (b,h,q)
__global__ __launch_bounds__(256)
void attn_sparse(const float* __restrict__ Q, const float* __restrict__ Kp,
                 const float* __restrict__ Vp, const int* __restrict__ IDX,
                 const int* __restrict__ CNT, float* __restrict__ O){
    int wid = threadIdx.x >> 6, lane = threadIdx.x & 63;
    int row = blockIdx.x * 4 + wid;            // B*H*LT rows
    int b = row / (NHH * LT);
    int rem = row % (NHH * LT);
    int h = rem / LT, i = rem % LT;
    int c = CNT[i];
    int jl = IDX[i * 12 + (lane % 12)];
    float qd = Q[(((size_t)b * LT + i) << 9) + h * 64 + lane];
    const float* kb = Kp + (((size_t)b * LT) << 9) + h * 64 + lane;
    const float* vb = Vp + (((size_t)b * LT) << 9) + h * 64 + lane;
    float m = -FLT_MAX, lsum = 0.f, o = 0.f;
    for (int t = 0; t < c; t++){
        int j = __shfl(jl, t, 64);
        float s = qd * kb[(size_t)j << 9];
        #pragma unroll
        for (int off = 32; off; off >>= 1) s += __shfl_xor(s, off, 64);
        s *= 0.125f;                            // 1/sqrt(64)
        float mn = fmaxf(m, s);
        float sc = __expf(m - mn);
        float p  = __expf(s - mn);
        lsum = lsum * sc + p;
        o = o * sc + p * vb[(size_t)j << 9];
        m = mn;
    }
    O[(((size_t)b * LT + i) << 9) + h * 64 + lane] = o / lsum;
}

// ---------------- dense flash attention with byte mask (semantic)
// grid: x = 22 q-tiles of 64, y = b*8+h. block 256 = 16x16.
__global__ __launch_bounds__(256)
void flash_attn(const float* __restrict__ Q, const float* __restrict__ Kp,
                const float* __restrict__ Vp, const uint8_t* __restrict__ Mk,
                long mbstride, float* __restrict__ O)
{
    __shared__ float Qs[64][65];   // [d][row]
    __shared__ float KP[64][65];   // K tile [d][key], then P tile [key][row]
    __shared__ float Vs[64][68];   // [key][d], pad 68 keeps float4 alignment
    int bh = blockIdx.y, b = bh >> 3, h = bh & 7;
    int q0 = blockIdx.x << 6;
    int tid = threadIdx.x, tx = tid & 15, ty = tid >> 4;

    const float* Qbase = Q + (((size_t)b * LT + q0) << 9) + h * 64;
    #pragma unroll
    for (int c = 0; c < 4; c++){
        int idx = tid + 256 * c;              // 0..1023
        int r = idx >> 4, d4 = (idx & 15) << 2;
        int rr = (q0 + r < LT) ? r : (LT - 1 - q0);
        float4 v = *(const float4*)(Qbase + ((size_t)rr << 9) + d4);
        Qs[d4+0][r] = v.x; Qs[d4+1][r] = v.y; Qs[d4+2][r] = v.z; Qs[d4+3][r] = v.w;
    }
    float acc[4][4] = {{0.f,0.f,0.f,0.f},{0.f,0.f,0.f,0.f},{0.f,0.f,0.f,0.f},{0.f,0.f,0.f,0.f}};
    float m_i[4] = {-FLT_MAX,-FLT_MAX,-FLT_MAX,-FLT_MAX};
    float l_i[4] = {0.f,0.f,0.f,0.f};
    const float* Kbase = Kp + (((size_t)b * LT) << 9) + h * 64;
    const float* Vbase = Vp + (((size_t)b * LT) << 9) + h * 64;
    const uint8_t* Mbase = Mk + (size_t)b * mbstride;

    for (int kt = 0; kt < 22; kt++){
        int k0 = kt << 6;
        __syncthreads();                       // prior PV done; Qs ready on kt=0
        #pragma unroll
        for (int c = 0; c < 4; c++){
            int idx = tid + 256 * c;
            int kk = idx >> 4, d4 = (idx & 15) << 2;
            int gk = k0 + kk; int gkc = (gk < LT) ? gk : (LT - 1);
            float4 kv = *(const float4*)(Kbase + ((size_t)gkc << 9) + d4);
            KP[d4+0][kk] = kv.x; KP[d4+1][kk] = kv.y; KP[d4+2][kk] = kv.z; KP[d4+3][kk] = kv.w;
            float4 vv = *(const float4*)(Vbase + ((size_t)gkc << 9) + d4);
            *(float4*)&Vs[kk][d4] = vv;
        }
        __syncthreads();
        // S = Q K^T (4x4 per thread)
        float s[4][4] = {{0.f,0.f,0.f,0.f},{0.f,0.f,0.f,0.f},{0.f,0.f,0.f,0.f},{0.f,0.f,0.f,0.f}};
        #pragma unroll 8
        for (int d = 0; d < 64; d++){
            float ar[4], br[4];
            #pragma unroll
            for (int i = 0; i < 4; i++) ar[i] = Qs[d][(ty<<2)+i];
            #pragma unroll
            for (int j = 0; j < 4; j++) br[j] = KP[d][(tx<<2)+j];
            #pragma unroll
            for (int i = 0; i < 4; i++)
                #pragma unroll
                for (int j = 0; j < 4; j++)
                    s[i][j] = fmaf(ar[i], br[j], s[i][j]);
        }
        // mask + scale + online softmax
        int kcol = k0 + (tx << 2);
        #pragma unroll
        for (int i = 0; i < 4; i++){
            int qr = q0 + (ty << 2) + i;
            int qrc = (qr < LT) ? qr : (LT - 1);
            uint32_t mw;
            if (kcol + 3 < LT) mw = *(const uint32_t*)(Mbase + (size_t)qrc * LT + kcol);
            else mw = 0xFFFFFFFFu;
            #pragma unroll
            for (int j = 0; j < 4; j++){
                float sv = s[i][j] * 0.125f;
                s[i][j] = ((mw >> (8*j)) & 0xFF) ? -FLT_MAX : sv;
            }
            float tmax = fmaxf(fmaxf(s[i][0], s[i][1]), fmaxf(s[i][2], s[i][3]));
            #pragma unroll
            for (int off = 1; off < 16; off <<= 1) tmax = fmaxf(tmax, __shfl_xor(tmax, off, 64));
            float mn = fmaxf(m_i[i], tmax);
            float alpha = __expf(m_i[i] - mn);
            float psum = 0.f;
            #pragma unroll
            for (int j = 0; j < 4; j++){
                float pv = (s[i][j] <= -1e30f) ? 0.f : __expf(s[i][j] - mn);
                s[i][j] = pv; psum += pv;
            }
            #pragma unroll
            for (int off = 1; off < 16; off <<= 1) psum += __shfl_xor(psum, off, 64);
            l_i[i] = l_i[i] * alpha + psum;
            m_i[i] = mn;
            #pragma unroll
            for (int j = 0; j < 4; j++) acc[i][j] *= alpha;
        }
        __syncthreads();                       // done reading K from KP
        #pragma unroll
        for (int i = 0; i < 4; i++)
            #pragma unroll
            for (int j = 0; j < 4; j++)
                KP[(tx<<2)+j][(ty<<2)+i] = s[i][j];   // P tile [key][row]
        __syncthreads();
        // O += P @ V
        #pragma unroll 8
        for (int kk = 0; kk < 64; kk++){
            float ar[4], br[4];
            #pragma unroll
            for (int i = 0; i < 4; i++) ar[i] = KP[kk][(ty<<2)+i];
            #pragma unroll
            for (int j = 0; j < 4; j++) br[j] = Vs[kk][(tx<<2)+j];
            #pragma unroll
            for (int i = 0; i < 4; i++)
                #pragma unroll
                for (int j = 0; j < 4; j++)
                    acc[i][j] = fmaf(ar[i], br[j], acc[i][j]);
        }
    }
    #pragma unroll
    for (int i = 0; i < 4; i++){
        int qr = q0 + (ty << 2) + i;
        if (qr < LT){
            float inv = 1.f / l_i[i];
            #pragma unroll
            for (int j = 0; j < 4; j++)
                O[(((size_t)b * LT + qr) << 9) + h * 64 + (tx << 2) + j] = acc[i][j] * inv;
        }
    }
}

// ---------------- x = (t + s + x)/3
__global__ __launch_bounds__(256)
void add3_kernel(const float* __restrict__ T, const float* __restrict__ S,
                 float* __restrict__ X){
    size_t idx = (size_t)blockIdx.x * 256 + threadIdx.x;
    X[idx] = (T[idx] + S[idx] + X[idx]) * (1.f / 3.f);
}

extern "C" void kernel_launch(void* const* d_in, const int* in_sizes, int n_in,
                              void* d_out, int out_size, void* d_ws, size_t ws_size,
                              hipStream_t stream)
{
    const float* x_enc   = (const float*)d_in[0];
    const float* down_W  = (const float*)d_in[1];
    const float* down_b  = (const float*)d_in[2];
    const float* conv_W  = (const float*)d_in[3];
    const float* conv_b  = (const float*)d_in[4];
    const float* up_W    = (const float*)d_in[5];
    const float* up_b    = (const float*)d_in[6];
    const float* bc_g    = (const float*)d_in[7];
    const float* bc_b    = (const float*)d_in[8];
    const float* aWq     = (const float*)d_in[9];
    const float* aWk     = (const float*)d_in[10];
    const float* aWv     = (const float*)d_in[11];
    const float* afcW    = (const float*)d_in[12];
    const float* afcb    = (const float*)d_in[13];
    const float* alng    = (const float*)d_in[14];
    const float* alnb    = (const float*)d_in[15];
    const float* fW1     = (const float*)d_in[16];
    const float* fb1     = (const float*)d_in[17];
    const float* fW2     = (const float*)d_in[18];
    const float* fb2     = (const float*)d_in[19];
    const float* flng    = (const float*)d_in[20];
    const float* flnb    = (const float*)d_in[21];

    const size_t NBL = (size_t)BB * LT * 512;   // 2,785,280
    float* X   = (float*)d_ws;
    float* TMP = X   + NBL;
    float* Qb  = TMP + NBL;
    float* Kb  = Qb  + NBL;
    float* Vb  = Kb  + NBL;
    float* AO  = Vb  + NBL;
    float* TO  = AO  + NBL;
    float* SO  = TO  + NBL;
    uint8_t* SM = (uint8_t*)(SO + NBL);          // B*LT*LT bytes (semantic banned mask)
    int* TIDX = (int*)(SM + (size_t)BB * LT * LT);
    int* TCNT = TIDX + (size_t)LT * 12;
    size_t need = 8 * NBL * sizeof(float) + (size_t)BB * LT * LT + (size_t)LT * 13 * 4;
    if (ws_size < need) return;

    // aliases (lifetimes disjoint)
    float* Y    = Qb;                 // down output (B,1024,512)
    float* C1   = Kb;                 // (B,256,512)
    float* C2   = C1 + (size_t)BB*256*512;
    float* C3   = C2 + (size_t)BB*64*512;
    float* PCAT = Vb;                 // (B,336,512)
    float* WR0  = TO;                 // 3 x (2048,512) repacked conv weights (spills into SO, unused then)
    float* WR1  = WR0 + (size_t)2048*512;
    float* WR2  = WR1 + (size_t)2048*512;
    float* XN   = AO;                 // normalized rows for semantic sim
    float* Hf   = Qb;                 // FFN hidden

    auto gemm = [&](const float* A, const float* Bm, const float* bias,
                    const float* res, float* C, int M, int N, int K,
                    int mpb, int orpb, int ooff, int act){
        dim3 grid(N / 64, M / 64);
        gemm_f32<<<grid, 256, 0, stream>>>(A, Bm, bias, res, C, M, N, K, mpb, orpb, ooff, act);
    };

    build_tidx<<<(LT + 255) / 256, 256, 0, stream>>>(TIDX, TCNT);
    repack_w<<<4096, 256, 0, stream>>>(conv_W + 0 * (size_t)512*512*4, WR0);
    repack_w<<<4096, 256, 0, stream>>>(conv_W + 1 * (size_t)512*512*4, WR1);
    repack_w<<<4096, 256, 0, stream>>>(conv_W + 2 * (size_t)512*512*4, WR2);

    // ---- bottleneck
    gemm(x_enc, down_W, down_b, nullptr, Y, BB*1024, 512, 512, BB*1024, 0, 0, 0);
    gemm(Y,  WR0, conv_b + 0,    nullptr, C1, BB*256, 512, 2048, BB*256, 0, 0, 1);
    gemm(C1, WR1, conv_b + 512,  nullptr, C2, BB*64,  512, 2048, BB*64,  0, 0, 1);
    gemm(C2, WR2, conv_b + 1024, nullptr, C3, BB*16,  512, 2048, BB*16,  0, 0, 1);
    pcat_copy<<<(BB*336*512)/256, 256, 0, stream>>>(C1, C2, C3, PCAT);
    gemm(PCAT, up_W, up_b, nullptr, TMP, BB*336, 512, 512, 336, LT, 1024, 0);
    xenc_copy<<<(BB*1024*512)/256, 256, 0, stream>>>(x_enc, TMP);
    ln_kernel<<<(BB*LT)/4, 256, 0, stream>>>(TMP, bc_g, bc_b, X, 1e-5f);

    // ---- transformer layers
    for (int l = 0; l < 2; l++){
        hipMemsetAsync(SM, 0, (size_t)BB * LT * LT, stream);
        rownorm_kernel<<<(BB*LT)/4, 256, 0, stream>>>(X, XN);
        topk_kernel<<<BB*LT, 256, 0, stream>>>(XN, SM);

        for (int j = 0; j < 2; j++){
            const float* Wq = aWq  + ((size_t)(l*2 + j)) * 512 * 512;
            const float* Wk = aWk  + ((size_t)(l*2 + j)) * 512 * 512;
            const float* Wv = aWv  + ((size_t)(l*2 + j)) * 512 * 512;
            const float* Wf = afcW + ((size_t)(l*2 + j)) * 512 * 512;
            const float* bf = afcb + (size_t)(l*2 + j) * 512;
            const float* lg = alng + (size_t)(l*2 + j) * 512;
            const float* lb = alnb + (size_t)(l*2 + j) * 512;
            gemm(X, Wq, nullptr, nullptr, Qb, BB*LT, 512, 512, BB*LT, 0, 0, 0);
            gemm(X, Wk, nullptr, nullptr, Kb, BB*LT, 512, 512, BB*LT, 0, 0, 0);
            gemm(X, Wv, nullptr, nullptr, Vb, BB*LT, 512, 512, BB*LT, 0, 0, 0);
            if (j == 0)
                attn_sparse<<<(BB*NHH*LT)/4, 256, 0, stream>>>(Qb, Kb, Vb, TIDX, TCNT, AO);
            else
                flash_attn<<<dim3(22, 32), 256, 0, stream>>>(Qb, Kb, Vb, SM, (long)LT*LT, AO);
            gemm(AO, Wf, bf, X, TMP, BB*LT, 512, 512, BB*LT, 0, 0, 0);
            ln_kernel<<<(BB*LT)/4, 256, 0, stream>>>(TMP, lg, lb, (j == 0) ? TO : SO, 1e-6f);
        }
        add3_kernel<<<(int)(NBL/256), 256, 0, stream>>>(TO, SO, X);

        // FFN
        gemm(X,  fW1 + (size_t)l*512*512, fb1 + (size_t)l*512, nullptr, Hf, BB*LT, 512, 512, BB*LT, 0, 0, 2);
        gemm(Hf, fW2 + (size_t)l*512*512, fb2 + (size_t)l*512, X,       TMP, BB*LT, 512, 512, BB*LT, 0, 0, 0);
        ln_kernel<<<(BB*LT)/4, 256, 0, stream>>>(TMP, flng + (size_t)l*512, flnb + (size_t)l*512,
                                                 (l == 1) ? (float*)d_out : X, 1e-6f);
    }
}

// Round 4
// 2944.794 us; speedup vs baseline: 1.5652x; 1.5652x over previous
//
#include <hip/hip_runtime.h>
#include <float.h>
#include <math.h>
#include <stdint.h>

#define LT 1360
#define BB 4
#define DM 512
#define NHH 8

// semantic sim buffer layout (per batch): group offsets and total
#define SG0 0
#define SG1 1048576            // 1024^2
#define SG2 (SG1 + 65536)      // + 256^2
#define SG3 (SG2 + 4096)       // + 64^2
#define SBT (SG3 + 256)        // + 16^2 = 1,118,464 floats per batch

// ---------------- block helpers (sizes 1024,256,64,16; starts 0,1024,1280,1344)
__device__ __forceinline__ void blk_info(int i, int& bi, int& st, int& n){
    if (i < 1024){ bi = 0; st = 0;    n = 1024; }
    else if (i < 1280){ bi = 1; st = 1024; n = 256; }
    else if (i < 1344){ bi = 2; st = 1280; n = 64; }
    else { bi = 3; st = 1344; n = 16; }
}

// ---------------- temporal allowed-index lists: TIDX[i*12+t], TCNT[i]
__global__ __launch_bounds__(256)
void build_tidx(int* __restrict__ idx, int* __restrict__ cnt){
    int i = blockIdx.x * 256 + threadIdx.x;
    if (i >= LT) return;
    int bi, st, n; blk_info(i, bi, st, n);
    int c = 0; int* row = idx + i * 12;
    int lo = (i - 2 > st) ? i - 2 : st;
    int hi = (i + 2 < st + n - 1) ? i + 2 : st + n - 1;
    for (int j = lo; j <= hi; j++) row[c++] = j;       // inner window (incl self)
    if (bi < 3) row[c++] = st + n + (i - st) / 4;      // parent in next (coarser) block
    if (bi > 0){                                        // 4 children in previous block
        int stc = st - n * 4;
        int base = stc + (i - st) * 4;
        for (int t = 0; t < 4; t++) row[c++] = base + t;
    }
    cnt[i] = c;
}

// ---------------- conv weight repack: wr[(k*512+ii)*512 + o] = cw[o][ii][k]
__global__ __launch_bounds__(256)
void repack_w(const float* __restrict__ cw, float* __restrict__ wr){
    int idx = blockIdx.x * 256 + threadIdx.x;   // 2048*512
    int p = idx >> 9;          // k*512+ii
    int o = idx & 511;
    int k = p >> 9;
    int ii = p & 511;
    wr[idx] = cw[((size_t)o * 512 + ii) * 4 + k];
}

// ---------------- generic fp32 GEMM, 64x64 tile, BK=16, 256 thr, 4x4/thread
__global__ __launch_bounds__(256)
void gemm_f32(const float* __restrict__ A, const float* __restrict__ Bm,
              const float* __restrict__ bias, const float* __restrict__ Rres,
              float* __restrict__ C, int M, int N, int K,
              int mpb, int orpb, int ooff, int act)
{
    __shared__ float As[16][65];
    __shared__ float Bs[16][68];
    int tid = threadIdx.x;
    int tx = tid & 15, ty = tid >> 4;
    int gm = blockIdx.y << 6, gn = blockIdx.x << 6;
    int lm = tid >> 2, lk4 = (tid & 3) << 2;
    int bk = tid >> 4, bn4 = (tid & 15) << 2;
    float acc[4][4] = {{0.f,0.f,0.f,0.f},{0.f,0.f,0.f,0.f},{0.f,0.f,0.f,0.f},{0.f,0.f,0.f,0.f}};
    for (int k0 = 0; k0 < K; k0 += 16){
        float4 av = *(const float4*)(A + (size_t)(gm + lm) * K + k0 + lk4);
        As[lk4+0][lm] = av.x; As[lk4+1][lm] = av.y;
        As[lk4+2][lm] = av.z; As[lk4+3][lm] = av.w;
        float4 bv = *(const float4*)(Bm + (size_t)(k0 + bk) * N + gn + bn4);
        *(float4*)&Bs[bk][bn4] = bv;
        __syncthreads();
        #pragma unroll
        for (int kk = 0; kk < 16; kk++){
            float ar[4], br[4];
            #pragma unroll
            for (int i = 0; i < 4; i++) ar[i] = As[kk][(ty<<2)+i];
            #pragma unroll
            for (int j = 0; j < 4; j++) br[j] = Bs[kk][(tx<<2)+j];
            #pragma unroll
            for (int i = 0; i < 4; i++)
                #pragma unroll
                for (int j = 0; j < 4; j++)
                    acc[i][j] = fmaf(ar[i], br[j], acc[i][j]);
        }
        __syncthreads();
    }
    const float cscale = 0.9999950000375f;   // 1/sqrt(1+1e-5)
    #pragma unroll
    for (int i = 0; i < 4; i++){
        int row = gm + (ty<<2) + i;
        int orow = (row / mpb) * orpb + ooff + (row % mpb);
        #pragma unroll
        for (int j = 0; j < 4; j++){
            int col = gn + (tx<<2) + j;
            float v = acc[i][j];
            if (bias) v += bias[col];
            if (Rres) v += Rres[(size_t)orow * N + col];
            if (act == 1){ v *= cscale; v = (v > 0.f) ? v : expm1f(v); }
            else if (act == 2){ v = fmaxf(v, 0.f); }
            C[(size_t)orow * N + col] = v;
        }
    }
}

// ---------------- semantic sim GEMM: SIM[b,grp][i][j] = dot(XN[st+i], XN[st+j])
// grid.x = 274 tiles (g0:256, g1:16, g2:1, g3:1), grid.y = batch
__global__ __launch_bounds__(256)
void sim_gemm(const float* __restrict__ XN, float* __restrict__ SIM){
    __shared__ float As[16][65];
    __shared__ float Bs[16][65];
    int x = blockIdx.x, b = blockIdx.y;
    int ti, tj, st, n, goff;
    if (x < 256){ ti = x >> 4; tj = x & 15; st = 0; n = 1024; goff = SG0; }
    else if (x < 272){ int y = x - 256; ti = y >> 2; tj = y & 3; st = 1024; n = 256; goff = SG1; }
    else if (x == 272){ ti = 0; tj = 0; st = 1280; n = 64; goff = SG2; }
    else { ti = 0; tj = 0; st = 1344; n = 16; goff = SG3; }
    const float* Xb = XN + (((size_t)b * LT + st) << 9);
    float* Cb = SIM + (size_t)b * SBT + goff;
    int gm = ti << 6, gn = tj << 6;
    int tid = threadIdx.x;
    int tx = tid & 15, ty = tid >> 4;
    int lm = tid >> 2, lk4 = (tid & 3) << 2;
    int ra = gm + lm; if (ra > n - 1) ra = n - 1;      // clamp (only g3)
    int rb = gn + lm; if (rb > n - 1) rb = n - 1;
    float acc[4][4] = {{0.f,0.f,0.f,0.f},{0.f,0.f,0.f,0.f},{0.f,0.f,0.f,0.f},{0.f,0.f,0.f,0.f}};
    for (int k0 = 0; k0 < 512; k0 += 16){
        float4 av = *(const float4*)(Xb + ((size_t)ra << 9) + k0 + lk4);
        As[lk4+0][lm] = av.x; As[lk4+1][lm] = av.y;
        As[lk4+2][lm] = av.z; As[lk4+3][lm] = av.w;
        float4 bv = *(const float4*)(Xb + ((size_t)rb << 9) + k0 + lk4);
        Bs[lk4+0][lm] = bv.x; Bs[lk4+1][lm] = bv.y;
        Bs[lk4+2][lm] = bv.z; Bs[lk4+3][lm] = bv.w;
        __syncthreads();
        #pragma unroll
        for (int kk = 0; kk < 16; kk++){
            float ar[4], br[4];
            #pragma unroll
            for (int i = 0; i < 4; i++) ar[i] = As[kk][(ty<<2)+i];
            #pragma unroll
            for (int j = 0; j < 4; j++) br[j] = Bs[kk][(tx<<2)+j];
            #pragma unroll
            for (int i = 0; i < 4; i++)
                #pragma unroll
                for (int j = 0; j < 4; j++)
                    acc[i][j] = fmaf(ar[i], br[j], acc[i][j]);
        }
        __syncthreads();
    }
    #pragma unroll
    for (int i = 0; i < 4; i++){
        int r = gm + (ty<<2) + i;
        if (r < n){
            #pragma unroll
            for (int j = 0; j < 4; j++){
                int c = gn + (tx<<2) + j;
                if (c < n) Cb[(size_t)r * n + c] = acc[i][j];
            }
        }
    }
}

// ---------------- concat conv pyramids
__global__ __launch_bounds__(256)
void pcat_copy(const float* __restrict__ C1, const float* __restrict__ C2,
               const float* __restrict__ C3, float* __restrict__ PC){
    int idx = blockIdx.x * 256 + threadIdx.x;   // 4*336*512
    int d = idx & 511;
    int r = (idx >> 9) % 336;
    int b = idx / (336 * 512);
    float v;
    if (r < 256)       v = C1[(((size_t)b * 256 + r) << 9) + d];
    else if (r < 320)  v = C2[(((size_t)b * 64 + (r - 256)) << 9) + d];
    else               v = C3[(((size_t)b * 16 + (r - 320)) << 9) + d];
    PC[idx] = v;
}

// ---------------- copy x_enc (B,1024,512) into rows [0,1024) of (B,1360,512)
__global__ __launch_bounds__(256)
void xenc_copy(const float* __restrict__ xe, float* __restrict__ dst){
    int idx = blockIdx.x * 256 + threadIdx.x;   // 4*1024*512
    int d = idx & 511;
    int l = (idx >> 9) & 1023;
    int b = idx >> 19;
    dst[(((size_t)b * LT + l) << 9) + d] = xe[idx];
}

// ---------------- LayerNorm over 512, wave per row
__global__ __launch_bounds__(256)
void ln_kernel(const float* __restrict__ in, const float* __restrict__ g,
               const float* __restrict__ bta, float* __restrict__ out, float eps){
    int wid = threadIdx.x >> 6, lane = threadIdx.x & 63;
    int row = blockIdx.x * 4 + wid;
    const float* p = in + ((size_t)row << 9);
    float vals[8]; float s = 0.f, s2 = 0.f;
    #pragma unroll
    for (int t = 0; t < 8; t++){
        float v = p[lane + t * 64]; vals[t] = v; s += v; s2 += v * v;
    }
    #pragma unroll
    for (int off = 32; off; off >>= 1){
        s  += __shfl_xor(s,  off, 64);
        s2 += __shfl_xor(s2, off, 64);
    }
    float mu = s * (1.f / 512.f);
    float var = s2 * (1.f / 512.f) - mu * mu;
    float r = rsqrtf(var + eps);
    float* q = out + ((size_t)row << 9);
    #pragma unroll
    for (int t = 0; t < 8; t++){
        int c = lane + t * 64;
        q[c] = (vals[t] - mu) * r * g[c] + bta[c];
    }
}

// ---------------- row L2-normalize, wave per row
__global__ __launch_bounds__(256)
void rownorm_kernel(const float* __restrict__ in, float* __restrict__ out){
    int wid = threadIdx.x >> 6, lane = threadIdx.x & 63;
    int row = blockIdx.x * 4 + wid;
    const float* p = in + ((size_t)row << 9);
    float vals[8]; float s2 = 0.f;
    #pragma unroll
    for (int t = 0; t < 8; t++){
        float v = p[lane + t * 64]; vals[t] = v; s2 += v * v;
    }
    #pragma unroll
    for (int off = 32; off; off >>= 1) s2 += __shfl_xor(s2, off, 64);
    float inv = 1.f / fmaxf(sqrtf(s2), 1e-8f);
    float* q = out + ((size_t)row << 9);
    #pragma unroll
    for (int t = 0; t < 8; t++) q[lane + t * 64] = vals[t] * inv;
}

// ---------------- top-k select from precomputed sim rows (radix select)
__device__ __forceinline__ uint32_t mono_key(float v){
    uint32_t b = __float_as_uint(v);
    return b ^ ((b & 0x80000000u) ? 0xFFFFFFFFu : 0x80000000u);
}

__global__ __launch_bounds__(256)
void topk_sel(const float* __restrict__ SIM, uint8_t* __restrict__ SM){
    __shared__ float sim[1024];
    __shared__ uint32_t hist[256];
    __shared__ int lidx[1024];
    __shared__ int scal[3];          // 0: cutoff bin, 1: cnt_gt, 2: boundary count
    int r = blockIdx.x;              // 0..B*LT-1
    int b = r / LT, i = r % LT;
    int bi, st, n; blk_info(i, bi, st, n);
    int goff = (bi == 0) ? SG0 : (bi == 1) ? SG1 : (bi == 2) ? SG2 : SG3;
    int tid = threadIdx.x;
    const float* srow = SIM + (size_t)b * SBT + goff + (size_t)(i - st) * n;
    hist[tid] = 0;
    if (tid == 0) scal[2] = 0;
    __syncthreads();
    for (int j4 = tid << 2; j4 < n; j4 += 1024){
        float4 v4 = *(const float4*)(srow + j4);
        *(float4*)&sim[j4] = v4;
        atomicAdd(&hist[mono_key(v4.x) >> 24], 1u);
        atomicAdd(&hist[mono_key(v4.y) >> 24], 1u);
        atomicAdd(&hist[mono_key(v4.z) >> 24], 1u);
        atomicAdd(&hist[mono_key(v4.w) >> 24], 1u);
    }
    __syncthreads();
    // suffix sum: hist[t] <- sum_{b>=t} hist[b]
    #pragma unroll
    for (int off = 1; off < 256; off <<= 1){
        uint32_t add = (tid + off < 256) ? hist[tid + off] : 0u;
        __syncthreads();
        hist[tid] += add;
        __syncthreads();
    }
    int k = (n < 32) ? n : 32;
    uint32_t ge = hist[tid];
    uint32_t gt = (tid < 255) ? hist[tid + 1] : 0u;
    if (ge >= (uint32_t)k && gt < (uint32_t)k){ scal[0] = tid; scal[1] = (int)gt; }
    __syncthreads();
    int Bcut = scal[0], C1 = scal[1];
    int R = k - C1;
    uint8_t* mrow = SM + ((size_t)b * LT + i) * LT + st;
    for (int j = tid; j < n; j += 256){
        int bin = (int)(mono_key(sim[j]) >> 24);
        if (bin > Bcut) mrow[j] = 1;
        else if (bin == Bcut){ int p = atomicAdd(&scal[2], 1); lidx[p] = j; }
    }
    __syncthreads();
    int cb = scal[2];
    for (int it = 0; it < R; it++){
        if (tid < 64){
            float bv = -FLT_MAX; int bj = 1 << 30;
            for (int p = tid; p < cb; p += 64){
                int j = lidx[p]; float v = sim[j];
                if (v > bv || (v == bv && j < bj)){ bv = v; bj = j; }
            }
            #pragma unroll
            for (int off = 32; off; off >>= 1){
                float ov = __shfl_xor(bv, off, 64);
                int   oj = __shfl_xor(bj, off, 64);
                if (ov > bv || (ov == bv && oj < bj)){ bv = ov; bj = oj; }
            }
            if (tid == 0){ mrow[bj] = 1; sim[bj] = -FLT_MAX; }
        }
        __syncthreads();
    }
}

// ---------------- sparse attention via index lists (temporal), wave per (b,h,q)
__global__ __launch_bounds__(256)
void attn_sparse(const float* __restrict__ Q, const float* __restrict__ Kp,
                 const float* __restrict__ Vp, const int* __restrict__ IDX,
                 const int* __restrict__ CNT, float* __restrict__ O){
    int wid = threadIdx.x >> 6, lane = threadIdx.x & 63;
    int row = blockIdx.x * 4 + wid;            // B*H*LT rows
    int b = row / (NHH * LT);
    int rem = row % (NHH * LT);
    int h = rem / LT, i = rem % LT;
    int c = CNT[i];
    int jl = IDX[i * 12 + (lane % 12)];
    float qd = Q[(((size_t)b * LT + i) << 9) + h * 64 + lane];
    const float* kb = Kp + (((size_t)b * LT) << 9) + h * 64 + lane;
    const float* vb = Vp + (((size_t)b * LT) << 9) + h * 64 + lane;
    float m = -FLT_MAX, lsum = 0.f, o = 0.f;
    for (int t = 0; t < c; t++){
        int j = __shfl(jl, t, 64);
        float s = qd * kb[(size_t)j << 9];
        #pragma unroll
        for (int off = 32; off; off >>= 1) s += __shfl_xor(s, off, 64);
        s *= 0.125f;                            // 1/sqrt(64)
        float mn = fmaxf(m, s);
        float sc = __expf(m - mn);
        float p  = __expf(s - mn);
        lsum = lsum * sc + p;
        o = o * sc + p * vb[(size_t)j << 9];
        m = mn;
    }
    O[(((size_t)b * LT + i) << 9) + h * 64 + lane] = o / lsum;
}

// ---------------- dense flash attention with byte mask (semantic)
__global__ __launch_bounds__(256)
void flash_attn(const float* __restrict__ Q, const float* __restrict__ Kp,
                const float* __restrict__ Vp, const uint8_t* __restrict__ Mk,
                long mbstride, float* __restrict__ O)
{
    __shared__ float Qs[64][65];   // [d][row]
    __shared__ float KP[64][65];   // K tile [d][key], then P tile [key][row]
    __shared__ float Vs[64][68];   // [key][d]
    int bh = blockIdx.y, b = bh >> 3, h = bh & 7;
    int q0 = blockIdx.x << 6;
    int tid = threadIdx.x, tx = tid & 15, ty = tid >> 4;

    const float* Qbase = Q + (((size_t)b * LT + q0) << 9) + h * 64;
    #pragma unroll
    for (int c = 0; c < 4; c++){
        int idx = tid + 256 * c;              // 0..1023
        int r = idx >> 4, d4 = (idx & 15) << 2;
        int rr = (q0 + r < LT) ? r : (LT - 1 - q0);
        float4 v = *(const float4*)(Qbase + ((size_t)rr << 9) + d4);
        Qs[d4+0][r] = v.x; Qs[d4+1][r] = v.y; Qs[d4+2][r] = v.z; Qs[d4+3][r] = v.w;
    }
    float acc[4][4] = {{0.f,0.f,0.f,0.f},{0.f,0.f,0.f,0.f},{0.f,0.f,0.f,0.f},{0.f,0.f,0.f,0.f}};
    float m_i[4] = {-FLT_MAX,-FLT_MAX,-FLT_MAX,-FLT_MAX};
    float l_i[4] = {0.f,0.f,0.f,0.f};
    const float* Kbase = Kp + (((size_t)b * LT) << 9) + h * 64;
    const float* Vbase = Vp + (((size_t)b * LT) << 9) + h * 64;
    const uint8_t* Mbase = Mk + (size_t)b * mbstride;

    for (int kt = 0; kt < 22; kt++){
        int k0 = kt << 6;
        __syncthreads();
        #pragma unroll
        for (int c = 0; c < 4; c++){
            int idx = tid + 256 * c;
            int kk = idx >> 4, d4 = (idx & 15) << 2;
            int gk = k0 + kk; int gkc = (gk < LT) ? gk : (LT - 1);
            float4 kv = *(const float4*)(Kbase + ((size_t)gkc << 9) + d4);
            KP[d4+0][kk] = kv.x; KP[d4+1][kk] = kv.y; KP[d4+2][kk] = kv.z; KP[d4+3][kk] = kv.w;
            float4 vv = *(const float4*)(Vbase + ((size_t)gkc << 9) + d4);
            *(float4*)&Vs[kk][d4] = vv;
        }
        __syncthreads();
        float s[4][4] = {{0.f,0.f,0.f,0.f},{0.f,0.f,0.f,0.f},{0.f,0.f,0.f,0.f},{0.f,0.f,0.f,0.f}};
        #pragma unroll 8
        for (int d = 0; d < 64; d++){
            float ar[4], br[4];
            #pragma unroll
            for (int i = 0; i < 4; i++) ar[i] = Qs[d][(ty<<2)+i];
            #pragma unroll
            for (int j = 0; j < 4; j++) br[j] = KP[d][(tx<<2)+j];
            #pragma unroll
            for (int i = 0; i < 4; i++)
                #pragma unroll
                for (int j = 0; j < 4; j++)
                    s[i][j] = fmaf(ar[i], br[j], s[i][j]);
        }
        int kcol = k0 + (tx << 2);
        #pragma unroll
        for (int i = 0; i < 4; i++){
            int qr = q0 + (ty << 2) + i;
            int qrc = (qr < LT) ? qr : (LT - 1);
            uint32_t mw;
            if (kcol + 3 < LT) mw = *(const uint32_t*)(Mbase + (size_t)qrc * LT + kcol);
            else mw = 0xFFFFFFFFu;
            #pragma unroll
            for (int j = 0; j < 4; j++){
                float sv = s[i][j] * 0.125f;
                s[i][j] = ((mw >> (8*j)) & 0xFF) ? -FLT_MAX : sv;
            }
            float tmax = fmaxf(fmaxf(s[i][0], s[i][1]), fmaxf(s[i][2], s[i][3]));
            #pragma unroll
            for (int off = 1; off < 16; off <<= 1) tmax = fmaxf(tmax, __shfl_xor(tmax, off, 64));
            float mn = fmaxf(m_i[i], tmax);
            float alpha = __expf(m_i[i] - mn);
            float psum = 0.f;
            #pragma unroll
            for (int j = 0; j < 4; j++){
                float pv = (s[i][j] <= -1e30f) ? 0.f : __expf(s[i][j] - mn);
                s[i][j] = pv; psum += pv;
            }
            #pragma unroll
            for (int off = 1; off < 16; off <<= 1) psum += __shfl_xor(psum, off, 64);
            l_i[i] = l_i[i] * alpha + psum;
            m_i[i] = mn;
            #pragma unroll
            for (int j = 0; j < 4; j++) acc[i][j] *= alpha;
        }
        __syncthreads();
        #pragma unroll
        for (int i = 0; i < 4; i++)
            #pragma unroll
            for (int j = 0; j < 4; j++)
                KP[(tx<<2)+j][(ty<<2)+i] = s[i][j];   // P tile [key][row]
        __syncthreads();
        #pragma unroll 8
        for (int kk = 0; kk < 64; kk++){
            float ar[4], br[4];
            #pragma unroll
            for (int i = 0; i < 4; i++) ar[i] = KP[kk][(ty<<2)+i];
            #pragma unroll
            for (int j = 0; j < 4; j++) br[j] = Vs[kk][(tx<<2)+j];
            #pragma unroll
            for (int i = 0; i < 4; i++)
                #pragma unroll
                for (int j = 0; j < 4; j++)
                    acc[i][j] = fmaf(ar[i], br[j], acc[i][j]);
        }
    }
    #pragma unroll
    for (int i = 0; i < 4; i++){
        int qr = q0 + (ty << 2) + i;
        if (qr < LT){
            float inv = 1.f / l_i[i];
            #pragma unroll
            for (int j = 0; j < 4; j++)
                O[(((size_t)b * LT + qr) << 9) + h * 64 + (tx << 2) + j] = acc[i][j] * inv;
        }
    }
}

// ---------------- x = (t + s + x)/3
__global__ __launch_bounds__(256)
void add3_kernel(const float* __restrict__ T, const float* __restrict__ S,
                 float* __restrict__ X){
    size_t idx = (size_t)blockIdx.x * 256 + threadIdx.x;
    X[idx] = (T[idx] + S[idx] + X[idx]) * (1.f / 3.f);
}

extern "C" void kernel_launch(void* const* d_in, const int* in_sizes, int n_in,
                              void* d_out, int out_size, void* d_ws, size_t ws_size,
                              hipStream_t stream)
{
    const float* x_enc   = (const float*)d_in[0];
    const float* down_W  = (const float*)d_in[1];
    const float* down_b  = (const float*)d_in[2];
    const float* conv_W  = (const float*)d_in[3];
    const float* conv_b  = (const float*)d_in[4];
    const float* up_W    = (const float*)d_in[5];
    const float* up_b    = (const float*)d_in[6];
    const float* bc_g    = (const float*)d_in[7];
    const float* bc_b    = (const float*)d_in[8];
    const float* aWq     = (const float*)d_in[9];
    const float* aWk     = (const float*)d_in[10];
    const float* aWv     = (const float*)d_in[11];
    const float* afcW    = (const float*)d_in[12];
    const float* afcb    = (const float*)d_in[13];
    const float* alng    = (const float*)d_in[14];
    const float* alnb    = (const float*)d_in[15];
    const float* fW1     = (const float*)d_in[16];
    const float* fb1     = (const float*)d_in[17];
    const float* fW2     = (const float*)d_in[18];
    const float* fb2     = (const float*)d_in[19];
    const float* flng    = (const float*)d_in[20];
    const float* flnb    = (const float*)d_in[21];

    const size_t NBL = (size_t)BB * LT * 512;   // 2,785,280
    float* X   = (float*)d_ws;
    float* TMP = X   + NBL;
    float* Qb  = TMP + NBL;
    float* Kb  = Qb  + NBL;
    float* Vb  = Kb  + NBL;
    float* AO  = Vb  + NBL;
    float* TO  = AO  + NBL;
    float* SO  = TO  + NBL;
    uint8_t* SM = (uint8_t*)(SO + NBL);          // B*LT*LT bytes (semantic banned mask)
    int* TIDX = (int*)(SM + (size_t)BB * LT * LT);
    int* TCNT = TIDX + (size_t)LT * 12;
    size_t need = 8 * NBL * sizeof(float) + (size_t)BB * LT * LT + (size_t)LT * 13 * 4;
    if (ws_size < need) return;

    // aliases (lifetimes disjoint)
    float* Y    = Qb;                 // down output (B,1024,512)
    float* C1   = Kb;                 // (B,256,512)
    float* C2   = C1 + (size_t)BB*256*512;
    float* C3   = C2 + (size_t)BB*64*512;
    float* PCAT = Vb;                 // (B,336,512)
    float* WR0  = TO;                 // 3 x (2048,512) repacked conv weights
    float* WR1  = WR0 + (size_t)2048*512;
    float* WR2  = WR1 + (size_t)2048*512;
    float* XN   = AO;                 // normalized rows for semantic sim
    float* SIMB = Qb;                 // sim blocks: 4*SBT = 4.47M floats, spans Qb+Kb (5.57M)
    float* Hf   = Qb;                 // FFN hidden

    auto gemm = [&](const float* A, const float* Bm, const float* bias,
                    const float* res, float* C, int M, int N, int K,
                    int mpb, int orpb, int ooff, int act){
        dim3 grid(N / 64, M / 64);
        gemm_f32<<<grid, 256, 0, stream>>>(A, Bm, bias, res, C, M, N, K, mpb, orpb, ooff, act);
    };

    build_tidx<<<(LT + 255) / 256, 256, 0, stream>>>(TIDX, TCNT);
    repack_w<<<4096, 256, 0, stream>>>(conv_W + 0 * (size_t)512*512*4, WR0);
    repack_w<<<4096, 256, 0, stream>>>(conv_W + 1 * (size_t)512*512*4, WR1);
    repack_w<<<4096, 256, 0, stream>>>(conv_W + 2 * (size_t)512*512*4, WR2);

    // ---- bottleneck
    gemm(x_enc, down_W, down_b, nullptr, Y, BB*1024, 512, 512, BB*1024, 0, 0, 0);
    gemm(Y,  WR0, conv_b + 0,    nullptr, C1, BB*256, 512, 2048, BB*256, 0, 0, 1);
    gemm(C1, WR1, conv_b + 512,  nullptr, C2, BB*64,  512, 2048, BB*64,  0, 0, 1);
    gemm(C2, WR2, conv_b + 1024, nullptr, C3, BB*16,  512, 2048, BB*16,  0, 0, 1);
    pcat_copy<<<(BB*336*512)/256, 256, 0, stream>>>(C1, C2, C3, PCAT);
    gemm(PCAT, up_W, up_b, nullptr, TMP, BB*336, 512, 512, 336, LT, 1024, 0);
    xenc_copy<<<(BB*1024*512)/256, 256, 0, stream>>>(x_enc, TMP);
    ln_kernel<<<(BB*LT)/4, 256, 0, stream>>>(TMP, bc_g, bc_b, X, 1e-5f);

    // ---- transformer layers
    for (int l = 0; l < 2; l++){
        hipMemsetAsync(SM, 0, (size_t)BB * LT * LT, stream);
        rownorm_kernel<<<(BB*LT)/4, 256, 0, stream>>>(X, XN);
        sim_gemm<<<dim3(274, BB), 256, 0, stream>>>(XN, SIMB);
        topk_sel<<<BB*LT, 256, 0, stream>>>(SIMB, SM);

        for (int j = 0; j < 2; j++){
            const float* Wq = aWq  + ((size_t)(l*2 + j)) * 512 * 512;
            const float* Wk = aWk  + ((size_t)(l*2 + j)) * 512 * 512;
            const float* Wv = aWv  + ((size_t)(l*2 + j)) * 512 * 512;
            const float* Wf = afcW + ((size_t)(l*2 + j)) * 512 * 512;
            const float* bf = afcb + (size_t)(l*2 + j) * 512;
            const float* lg = alng + (size_t)(l*2 + j) * 512;
            const float* lb = alnb + (size_t)(l*2 + j) * 512;
            gemm(X, Wq, nullptr, nullptr, Qb, BB*LT, 512, 512, BB*LT, 0, 0, 0);
            gemm(X, Wk, nullptr, nullptr, Kb, BB*LT, 512, 512, BB*LT, 0, 0, 0);
            gemm(X, Wv, nullptr, nullptr, Vb, BB*LT, 512, 512, BB*LT, 0, 0, 0);
            if (j == 0)
                attn_sparse<<<(BB*NHH*LT)/4, 256, 0, stream>>>(Qb, Kb, Vb, TIDX, TCNT, AO);
            else
                flash_attn<<<dim3(22, 32), 256, 0, stream>>>(Qb, Kb, Vb, SM, (long)LT*LT, AO);
            gemm(AO, Wf, bf, X, TMP, BB*LT, 512, 512, BB*LT, 0, 0, 0);
            ln_kernel<<<(BB*LT)/4, 256, 0, stream>>>(TMP, lg, lb, (j == 0) ? TO : SO, 1e-6f);
        }
        add3_kernel<<<(int)(NBL/256), 256, 0, stream>>>(TO, SO, X);

        // FFN
        gemm(X,  fW1 + (size_t)l*512*512, fb1 + (size_t)l*512, nullptr, Hf, BB*LT, 512, 512, BB*LT, 0, 0, 2);
        gemm(Hf, fW2 + (size_t)l*512*512, fb2 + (size_t)l*512, X,       TMP, BB*LT, 512, 512, BB*LT, 0, 0, 0);
        ln_kernel<<<(BB*LT)/4, 256, 0, stream>>>(TMP, flng + (size_t)l*512, flnb + (size_t)l*512,
                                                 (l == 1) ? (float*)d_out : X, 1e-6f);
    }
}

// Round 5
// 1538.458 us; speedup vs baseline: 2.9960x; 1.9141x over previous
//
#include <hip/hip_runtime.h>
#include <float.h>
#include <math.h>
#include <stdint.h>

#define LT 1360
#define BB 4
#define DM 512
#define NHH 8

typedef __attribute__((ext_vector_type(8))) short short8;
typedef __attribute__((ext_vector_type(4))) float f32x4;

__device__ __forceinline__ ushort f2b(float x){
    uint32_t u = __float_as_uint(x);
    return (ushort)((u + 0x7fffu + ((u >> 16) & 1u)) >> 16);
}
__device__ __forceinline__ float b2f(ushort u){
    return __uint_as_float(((uint32_t)u) << 16);
}

// semantic sim buffer layout (per batch)
#define SG0 0
#define SG1 1048576
#define SG2 (SG1 + 65536)
#define SG3 (SG2 + 4096)
#define SBT (SG3 + 256)

__device__ __forceinline__ void blk_info(int i, int& bi, int& st, int& n){
    if (i < 1024){ bi = 0; st = 0;    n = 1024; }
    else if (i < 1280){ bi = 1; st = 1024; n = 256; }
    else if (i < 1344){ bi = 2; st = 1280; n = 64; }
    else { bi = 3; st = 1344; n = 16; }
}

// ---------------- temporal allowed-index lists
__global__ __launch_bounds__(256)
void build_tidx(int* __restrict__ idx, int* __restrict__ cnt){
    int i = blockIdx.x * 256 + threadIdx.x;
    if (i >= LT) return;
    int bi, st, n; blk_info(i, bi, st, n);
    int c = 0; int* row = idx + i * 12;
    int lo = (i - 2 > st) ? i - 2 : st;
    int hi = (i + 2 < st + n - 1) ? i + 2 : st + n - 1;
    for (int j = lo; j <= hi; j++) row[c++] = j;
    if (bi < 3) row[c++] = st + n + (i - st) / 4;
    if (bi > 0){
        int stc = st - n * 4;
        int base = stc + (i - st) * 4;
        for (int t = 0; t < 4; t++) row[c++] = base + t;
    }
    cnt[i] = c;
}

// ---------------- weight transpose+cast: Wt[mat][n*K+k] = bf16(W[mat][k*N+n])
__global__ __launch_bounds__(256)
void wtrans(const float* __restrict__ W, ushort* __restrict__ Wt, int K, int N){
    int mat = blockIdx.z;
    const float* Ws = W + (size_t)mat * K * N;
    ushort* Wd = Wt + (size_t)mat * K * N;
    int k0 = blockIdx.y << 6, n0 = blockIdx.x << 6;
    __shared__ ushort t[64][72];
    int tid = threadIdx.x;
    #pragma unroll
    for (int p = 0; p < 4; p++){
        int idx = tid + (p << 8);
        int r = idx >> 4, c4 = (idx & 15) << 2;
        float4 v = *(const float4*)(Ws + (size_t)(k0 + r) * N + n0 + c4);
        t[c4+0][r] = f2b(v.x); t[c4+1][r] = f2b(v.y);
        t[c4+2][r] = f2b(v.z); t[c4+3][r] = f2b(v.w);
    }
    __syncthreads();
    #pragma unroll
    for (int p = 0; p < 4; p++){
        int idx = tid + (p << 8);
        int r = idx >> 4, c4 = (idx & 15) << 2;
        *(uint2*)&Wd[(size_t)(n0 + r) * K + k0 + c4] = *(uint2*)&t[r][c4];
    }
}

// ---------------- conv weight repack+cast: dst[o*2048 + k*512 + ii] = cw[o][ii][k]
__global__ __launch_bounds__(256)
void wconv(const float* __restrict__ cw, ushort* __restrict__ wt){
    int conv = blockIdx.y;
    const float* src = cw + (size_t)conv * 512 * 512 * 4;
    ushort* dst = wt + (size_t)conv * 2048 * 512;
    int idx = blockIdx.x * 256 + threadIdx.x;
    int o = idx >> 11, rest = idx & 2047;
    int k = rest >> 9, ii = rest & 511;
    dst[idx] = f2b(src[((size_t)(o << 9) + ii) * 4 + k]);
}

// ---------------- bf16 MFMA GEMM, 64x64 tile, BK=32, 256 thr / 4 waves
// A fp32 [M][K] (converted in staging), Bw bf16 [N][K] (B^T layout).
// act: 0 none, 1 ELU(cscale*(v)), 2 relu
// omode: 0 f32 out (with optional mpb/orpb/ooff row remap), 1 bf16 out, 2 bf16 transposed (V^T)
__global__ __launch_bounds__(256)
void gemm_bf16(const float* __restrict__ A, const ushort* __restrict__ Bw,
               const float* __restrict__ bias, const float* __restrict__ Rres,
               void* __restrict__ Cout, int M, int N, int K,
               int act, int omode, int mpb, int orpb, int ooff)
{
    __shared__ ushort As[64][40];
    __shared__ ushort Bs[64][40];
    int tid = threadIdx.x;
    int lane = tid & 63, w = tid >> 6, quad = lane >> 4, l15 = lane & 15;
    int gm = blockIdx.y << 6, gn = blockIdx.x << 6;
    int wr = (w >> 1) << 5, wc = (w & 1) << 5;
    int srow = tid >> 2, sc8 = (tid & 3) << 3;
    f32x4 acc[2][2] = {{{0.f,0.f,0.f,0.f},{0.f,0.f,0.f,0.f}},{{0.f,0.f,0.f,0.f},{0.f,0.f,0.f,0.f}}};
    const float* Arow = A + (size_t)(gm + srow) * K;
    const ushort* Brow = Bw + (size_t)(gn + srow) * K;
    for (int k0 = 0; k0 < K; k0 += 32){
        float4 a0 = *(const float4*)(Arow + k0 + sc8);
        float4 a1 = *(const float4*)(Arow + k0 + sc8 + 4);
        uint32_t p0 = (uint32_t)f2b(a0.x) | ((uint32_t)f2b(a0.y) << 16);
        uint32_t p1 = (uint32_t)f2b(a0.z) | ((uint32_t)f2b(a0.w) << 16);
        uint32_t p2 = (uint32_t)f2b(a1.x) | ((uint32_t)f2b(a1.y) << 16);
        uint32_t p3 = (uint32_t)f2b(a1.z) | ((uint32_t)f2b(a1.w) << 16);
        uint4 av; av.x = p0; av.y = p1; av.z = p2; av.w = p3;
        *(uint4*)&As[srow][sc8] = av;
        *(uint4*)&Bs[srow][sc8] = *(const uint4*)(Brow + k0 + sc8);
        __syncthreads();
        short8 af0 = *(const short8*)&As[wr + l15][quad << 3];
        short8 af1 = *(const short8*)&As[wr + 16 + l15][quad << 3];
        short8 bf0 = *(const short8*)&Bs[wc + l15][quad << 3];
        short8 bf1 = *(const short8*)&Bs[wc + 16 + l15][quad << 3];
        acc[0][0] = __builtin_amdgcn_mfma_f32_16x16x32_bf16(af0, bf0, acc[0][0], 0, 0, 0);
        acc[0][1] = __builtin_amdgcn_mfma_f32_16x16x32_bf16(af0, bf1, acc[0][1], 0, 0, 0);
        acc[1][0] = __builtin_amdgcn_mfma_f32_16x16x32_bf16(af1, bf0, acc[1][0], 0, 0, 0);
        acc[1][1] = __builtin_amdgcn_mfma_f32_16x16x32_bf16(af1, bf1, acc[1][1], 0, 0, 0);
        __syncthreads();
    }
    const float cscale = 0.9999950000375f;
    #pragma unroll
    for (int mi = 0; mi < 2; mi++){
        #pragma unroll
        for (int r = 0; r < 4; r++){
            int row = gm + wr + (mi << 4) + (quad << 2) + r;
            #pragma unroll
            for (int ni = 0; ni < 2; ni++){
                int col = gn + wc + (ni << 4) + l15;
                float v = acc[mi][ni][r];
                if (bias) v += bias[col];
                if (Rres) v += Rres[(size_t)row * N + col];
                if (act == 1){ v *= cscale; v = (v > 0.f) ? v : expm1f(v); }
                else if (act == 2){ v = fmaxf(v, 0.f); }
                if (omode == 0){
                    int orow = mpb ? (row / mpb) * orpb + ooff + (row % mpb) : row;
                    ((float*)Cout)[(size_t)orow * N + col] = v;
                } else if (omode == 1){
                    ((ushort*)Cout)[(size_t)row * N + col] = f2b(v);
                } else {
                    int bb = row / LT, ii = row - bb * LT;
                    ((ushort*)Cout)[((size_t)(bb * 512 + col)) * LT + ii] = f2b(v);
                }
            }
        }
    }
}

// ---------------- semantic sim GEMM (fp32 — feeds discrete top-k selection)
__global__ __launch_bounds__(256)
void sim_gemm(const float* __restrict__ XN, float* __restrict__ SIM){
    __shared__ float As[16][65];
    __shared__ float Bs[16][65];
    int x = blockIdx.x, b = blockIdx.y;
    int ti, tj, st, n, goff;
    if (x < 256){ ti = x >> 4; tj = x & 15; st = 0; n = 1024; goff = SG0; }
    else if (x < 272){ int y = x - 256; ti = y >> 2; tj = y & 3; st = 1024; n = 256; goff = SG1; }
    else if (x == 272){ ti = 0; tj = 0; st = 1280; n = 64; goff = SG2; }
    else { ti = 0; tj = 0; st = 1344; n = 16; goff = SG3; }
    const float* Xb = XN + (((size_t)b * LT + st) << 9);
    float* Cb = SIM + (size_t)b * SBT + goff;
    int gm = ti << 6, gn = tj << 6;
    int tid = threadIdx.x;
    int tx = tid & 15, ty = tid >> 4;
    int lm = tid >> 2, lk4 = (tid & 3) << 2;
    int ra = gm + lm; if (ra > n - 1) ra = n - 1;
    int rb = gn + lm; if (rb > n - 1) rb = n - 1;
    float acc[4][4] = {{0.f,0.f,0.f,0.f},{0.f,0.f,0.f,0.f},{0.f,0.f,0.f,0.f},{0.f,0.f,0.f,0.f}};
    for (int k0 = 0; k0 < 512; k0 += 16){
        float4 av = *(const float4*)(Xb + ((size_t)ra << 9) + k0 + lk4);
        As[lk4+0][lm] = av.x; As[lk4+1][lm] = av.y;
        As[lk4+2][lm] = av.z; As[lk4+3][lm] = av.w;
        float4 bv = *(const float4*)(Xb + ((size_t)rb << 9) + k0 + lk4);
        Bs[lk4+0][lm] = bv.x; Bs[lk4+1][lm] = bv.y;
        Bs[lk4+2][lm] = bv.z; Bs[lk4+3][lm] = bv.w;
        __syncthreads();
        #pragma unroll
        for (int kk = 0; kk < 16; kk++){
            float ar[4], br[4];
            #pragma unroll
            for (int i = 0; i < 4; i++) ar[i] = As[kk][(ty<<2)+i];
            #pragma unroll
            for (int j = 0; j < 4; j++) br[j] = Bs[kk][(tx<<2)+j];
            #pragma unroll
            for (int i = 0; i < 4; i++)
                #pragma unroll
                for (int j = 0; j < 4; j++)
                    acc[i][j] = fmaf(ar[i], br[j], acc[i][j]);
        }
        __syncthreads();
    }
    #pragma unroll
    for (int i = 0; i < 4; i++){
        int r = gm + (ty<<2) + i;
        if (r < n){
            #pragma unroll
            for (int j = 0; j < 4; j++){
                int c = gn + (tx<<2) + j;
                if (c < n) Cb[(size_t)r * n + c] = acc[i][j];
            }
        }
    }
}

// ---------------- concat conv pyramids
__global__ __launch_bounds__(256)
void pcat_copy(const float* __restrict__ C1, const float* __restrict__ C2,
               const float* __restrict__ C3, float* __restrict__ PC){
    int idx = blockIdx.x * 256 + threadIdx.x;
    int d = idx & 511;
    int r = (idx >> 9) % 336;
    int b = idx / (336 * 512);
    float v;
    if (r < 256)       v = C1[(((size_t)b * 256 + r) << 9) + d];
    else if (r < 320)  v = C2[(((size_t)b * 64 + (r - 256)) << 9) + d];
    else               v = C3[(((size_t)b * 16 + (r - 320)) << 9) + d];
    PC[idx] = v;
}

__global__ __launch_bounds__(256)
void xenc_copy(const float* __restrict__ xe, float* __restrict__ dst){
    int idx = blockIdx.x * 256 + threadIdx.x;
    int d = idx & 511;
    int l = (idx >> 9) & 1023;
    int b = idx >> 19;
    dst[(((size_t)b * LT + l) << 9) + d] = xe[idx];
}

// ---------------- LayerNorm over 512, wave per row
__global__ __launch_bounds__(256)
void ln_kernel(const float* __restrict__ in, const float* __restrict__ g,
               const float* __restrict__ bta, float* __restrict__ out, float eps){
    int wid = threadIdx.x >> 6, lane = threadIdx.x & 63;
    int row = blockIdx.x * 4 + wid;
    const float* p = in + ((size_t)row << 9);
    float vals[8]; float s = 0.f, s2 = 0.f;
    #pragma unroll
    for (int t = 0; t < 8; t++){
        float v = p[lane + t * 64]; vals[t] = v; s += v; s2 += v * v;
    }
    #pragma unroll
    for (int off = 32; off; off >>= 1){
        s  += __shfl_xor(s,  off, 64);
        s2 += __shfl_xor(s2, off, 64);
    }
    float mu = s * (1.f / 512.f);
    float var = s2 * (1.f / 512.f) - mu * mu;
    float r = rsqrtf(var + eps);
    float* q = out + ((size_t)row << 9);
    #pragma unroll
    for (int t = 0; t < 8; t++){
        int c = lane + t * 64;
        q[c] = (vals[t] - mu) * r * g[c] + bta[c];
    }
}

__global__ __launch_bounds__(256)
void rownorm_kernel(const float* __restrict__ in, float* __restrict__ out){
    int wid = threadIdx.x >> 6, lane = threadIdx.x & 63;
    int row = blockIdx.x * 4 + wid;
    const float* p = in + ((size_t)row << 9);
    float vals[8]; float s2 = 0.f;
    #pragma unroll
    for (int t = 0; t < 8; t++){
        float v = p[lane + t * 64]; vals[t] = v; s2 += v * v;
    }
    #pragma unroll
    for (int off = 32; off; off >>= 1) s2 += __shfl_xor(s2, off, 64);
    float inv = 1.f / fmaxf(sqrtf(s2), 1e-8f);
    float* q = out + ((size_t)row << 9);
    #pragma unroll
    for (int t = 0; t < 8; t++) q[lane + t * 64] = vals[t] * inv;
}

// ---------------- top-k radix select (fp32)
__device__ __forceinline__ uint32_t mono_key(float v){
    uint32_t b = __float_as_uint(v);
    return b ^ ((b & 0x80000000u) ? 0xFFFFFFFFu : 0x80000000u);
}

__global__ __launch_bounds__(256)
void topk_sel(const float* __restrict__ SIM, uint8_t* __restrict__ SM){
    __shared__ float sim[1024];
    __shared__ uint32_t hist[256];
    __shared__ int lidx[1024];
    __shared__ int scal[3];
    int r = blockIdx.x;
    int b = r / LT, i = r % LT;
    int bi, st, n; blk_info(i, bi, st, n);
    int goff = (bi == 0) ? SG0 : (bi == 1) ? SG1 : (bi == 2) ? SG2 : SG3;
    int tid = threadIdx.x;
    const float* srow = SIM + (size_t)b * SBT + goff + (size_t)(i - st) * n;
    hist[tid] = 0;
    if (tid == 0) scal[2] = 0;
    __syncthreads();
    for (int j4 = tid << 2; j4 < n; j4 += 1024){
        float4 v4 = *(const float4*)(srow + j4);
        *(float4*)&sim[j4] = v4;
        atomicAdd(&hist[mono_key(v4.x) >> 24], 1u);
        atomicAdd(&hist[mono_key(v4.y) >> 24], 1u);
        atomicAdd(&hist[mono_key(v4.z) >> 24], 1u);
        atomicAdd(&hist[mono_key(v4.w) >> 24], 1u);
    }
    __syncthreads();
    #pragma unroll
    for (int off = 1; off < 256; off <<= 1){
        uint32_t add = (tid + off < 256) ? hist[tid + off] : 0u;
        __syncthreads();
        hist[tid] += add;
        __syncthreads();
    }
    int k = (n < 32) ? n : 32;
    uint32_t ge = hist[tid];
    uint32_t gt = (tid < 255) ? hist[tid + 1] : 0u;
    if (ge >= (uint32_t)k && gt < (uint32_t)k){ scal[0] = tid; scal[1] = (int)gt; }
    __syncthreads();
    int Bcut = scal[0], C1 = scal[1];
    int R = k - C1;
    uint8_t* mrow = SM + ((size_t)b * LT + i) * LT + st;
    for (int j = tid; j < n; j += 256){
        int bin = (int)(mono_key(sim[j]) >> 24);
        if (bin > Bcut) mrow[j] = 1;
        else if (bin == Bcut){ int p = atomicAdd(&scal[2], 1); lidx[p] = j; }
    }
    __syncthreads();
    int cb = scal[2];
    for (int it = 0; it < R; it++){
        if (tid < 64){
            float bv = -FLT_MAX; int bj = 1 << 30;
            for (int p = tid; p < cb; p += 64){
                int j = lidx[p]; float v = sim[j];
                if (v > bv || (v == bv && j < bj)){ bv = v; bj = j; }
            }
            #pragma unroll
            for (int off = 32; off; off >>= 1){
                float ov = __shfl_xor(bv, off, 64);
                int   oj = __shfl_xor(bj, off, 64);
                if (ov > bv || (ov == bv && oj < bj)){ bv = ov; bj = oj; }
            }
            if (tid == 0){ mrow[bj] = 1; sim[bj] = -FLT_MAX; }
        }
        __syncthreads();
    }
}

// ---------------- sparse temporal attention (bf16 inputs, V transposed)
__global__ __launch_bounds__(256)
void attn_sparse(const ushort* __restrict__ Q, const ushort* __restrict__ Kp,
                 const ushort* __restrict__ Vt, const int* __restrict__ IDX,
                 const int* __restrict__ CNT, float* __restrict__ O){
    int wid = threadIdx.x >> 6, lane = threadIdx.x & 63;
    int row = blockIdx.x * 4 + wid;
    int b = row / (NHH * LT);
    int rem = row % (NHH * LT);
    int h = rem / LT, i = rem % LT;
    int c = CNT[i];
    int jl = IDX[i * 12 + (lane % 12)];
    float qd = b2f(Q[(((size_t)b * LT + i) << 9) + h * 64 + lane]);
    const ushort* kb = Kp + (((size_t)b * LT) << 9) + h * 64 + lane;
    const ushort* vb = Vt + ((size_t)(b * 512 + h * 64 + lane)) * LT;
    float m = -FLT_MAX, lsum = 0.f, o = 0.f;
    for (int t = 0; t < c; t++){
        int j = __shfl(jl, t, 64);
        float s = qd * b2f(kb[(size_t)j << 9]);
        #pragma unroll
        for (int off = 32; off; off >>= 1) s += __shfl_xor(s, off, 64);
        s *= 0.125f;
        float mn = fmaxf(m, s);
        float sc = __expf(m - mn);
        float p  = __expf(s - mn);
        lsum = lsum * sc + p;
        o = o * sc + p * b2f(vb[j]);
        m = mn;
    }
    O[(((size_t)b * LT + i) << 9) + h * 64 + lane] = o / lsum;
}

// ---------------- MFMA flash attention (semantic, byte mask)
// grid: x = 22 q-tiles of 64, y = b*8+h. 256 thr / 4 waves; wave = 16 q-rows.
__global__ __launch_bounds__(256)
void flash_mfma(const ushort* __restrict__ Q, const ushort* __restrict__ Kp,
                const ushort* __restrict__ Vt, const uint8_t* __restrict__ Mk,
                float* __restrict__ O)
{
    __shared__ ushort Ks[64][72];       // [key][d]
    __shared__ ushort Vs[64][72];       // [d][key]  (from V^T)
    __shared__ uint8_t Ms[64][64];      // [qrow][kcol]
    __shared__ ushort Ps[4][16][72];    // per-wave P strip [row][key]
    int bh = blockIdx.y, b = bh >> 3, h = bh & 7;
    int q0 = blockIdx.x << 6;
    int tid = threadIdx.x;
    int w = tid >> 6, lane = tid & 63, quad = lane >> 4, l15 = lane & 15;

    int qm = q0 + w * 16 + l15;
    int qmc = (qm < LT) ? qm : (LT - 1);
    const ushort* qp = Q + ((size_t)(b * LT + qmc) << 9) + h * 64 + (quad << 3);
    short8 qf0 = *(const short8*)qp;
    short8 qf1 = *(const short8*)(qp + 32);

    float m_i[4] = {-FLT_MAX, -FLT_MAX, -FLT_MAX, -FLT_MAX};
    float l_i[4] = {0.f, 0.f, 0.f, 0.f};
    f32x4 Oacc[4] = {{0.f,0.f,0.f,0.f},{0.f,0.f,0.f,0.f},{0.f,0.f,0.f,0.f},{0.f,0.f,0.f,0.f}};

    int srow = tid >> 2, sc = (tid & 3) << 4;
    const uint8_t* Mbase = Mk + (size_t)b * LT * LT;

    for (int kt = 0; kt < 22; kt++){
        int k0 = kt << 6;
        __syncthreads();
        // stage K tile [key][d]
        {
            int krow = k0 + srow; if (krow >= LT) krow = LT - 1;
            const ushort* kp = Kp + ((size_t)(b * LT + krow) << 9) + h * 64 + sc;
            *(uint4*)&Ks[srow][sc]     = *(const uint4*)kp;
            *(uint4*)&Ks[srow][sc + 8] = *(const uint4*)(kp + 8);
            // stage V^T tile [d][key]
            int kbase = k0 + sc; if (kbase > LT - 16) kbase = LT - 16;
            const ushort* vp = Vt + ((size_t)(b * 512 + h * 64 + srow)) * LT + kbase;
            *(uint4*)&Vs[srow][sc]     = *(const uint4*)vp;
            *(uint4*)&Vs[srow][sc + 8] = *(const uint4*)(vp + 8);
            // stage mask tile [qrow][kcol]
            int mrow = q0 + srow; if (mrow >= LT) mrow = LT - 1;
            *(uint4*)&Ms[srow][sc] = *(const uint4*)(Mbase + (size_t)mrow * LT + k0 + sc);
        }
        __syncthreads();
        // S = Q K^T : 4 n-tiles x 2 k-halves
        f32x4 s[4] = {{0.f,0.f,0.f,0.f},{0.f,0.f,0.f,0.f},{0.f,0.f,0.f,0.f},{0.f,0.f,0.f,0.f}};
        #pragma unroll
        for (int nt = 0; nt < 4; nt++){
            short8 kf0 = *(const short8*)&Ks[(nt << 4) + l15][quad << 3];
            short8 kf1 = *(const short8*)&Ks[(nt << 4) + l15][32 + (quad << 3)];
            s[nt] = __builtin_amdgcn_mfma_f32_16x16x32_bf16(qf0, kf0, s[nt], 0, 0, 0);
            s[nt] = __builtin_amdgcn_mfma_f32_16x16x32_bf16(qf1, kf1, s[nt], 0, 0, 0);
        }
        // mask + online softmax per row (row = quad*4 + r), stats replicated across l15
        float alpha[4];
        #pragma unroll
        for (int r = 0; r < 4; r++){
            int lrow = (w << 4) + (quad << 2) + r;
            float sv[4]; bool bad[4];
            #pragma unroll
            for (int nt = 0; nt < 4; nt++){
                int kcol = k0 + (nt << 4) + l15;
                uint32_t mw = *(const uint32_t*)&Ms[lrow][(nt << 4) + (l15 & ~3)];
                uint8_t mb = (uint8_t)(mw >> ((l15 & 3) << 3));
                bad[nt] = (mb != 0) || (kcol >= LT);
                sv[nt] = s[nt][r] * 0.125f;
            }
            float tmax = -FLT_MAX;
            #pragma unroll
            for (int nt = 0; nt < 4; nt++) if (!bad[nt]) tmax = fmaxf(tmax, sv[nt]);
            #pragma unroll
            for (int off = 1; off < 16; off <<= 1) tmax = fmaxf(tmax, __shfl_xor(tmax, off, 64));
            float mn = fmaxf(m_i[r], tmax);
            alpha[r] = __expf(m_i[r] - mn);
            float psum = 0.f;
            float pv[4];
            #pragma unroll
            for (int nt = 0; nt < 4; nt++){
                pv[nt] = bad[nt] ? 0.f : __expf(sv[nt] - mn);
                psum += pv[nt];
            }
            #pragma unroll
            for (int off = 1; off < 16; off <<= 1) psum += __shfl_xor(psum, off, 64);
            l_i[r] = l_i[r] * alpha[r] + psum;
            m_i[r] = mn;
            #pragma unroll
            for (int nt = 0; nt < 4; nt++)
                Ps[w][(quad << 2) + r][(nt << 4) + l15] = f2b(pv[nt]);
        }
        // rescale O
        #pragma unroll
        for (int dt = 0; dt < 4; dt++)
            #pragma unroll
            for (int r = 0; r < 4; r++)
                Oacc[dt][r] *= alpha[r];
        // O += P V   (A = P strip, B = V^T tile)
        short8 pf0 = *(const short8*)&Ps[w][l15][quad << 3];
        short8 pf1 = *(const short8*)&Ps[w][l15][32 + (quad << 3)];
        #pragma unroll
        for (int dt = 0; dt < 4; dt++){
            short8 vf0 = *(const short8*)&Vs[(dt << 4) + l15][quad << 3];
            short8 vf1 = *(const short8*)&Vs[(dt << 4) + l15][32 + (quad << 3)];
            Oacc[dt] = __builtin_amdgcn_mfma_f32_16x16x32_bf16(pf0, vf0, Oacc[dt], 0, 0, 0);
            Oacc[dt] = __builtin_amdgcn_mfma_f32_16x16x32_bf16(pf1, vf1, Oacc[dt], 0, 0, 0);
        }
    }
    #pragma unroll
    for (int r = 0; r < 4; r++){
        int qrow = q0 + (w << 4) + (quad << 2) + r;
        if (qrow < LT){
            float inv = 1.f / l_i[r];
            #pragma unroll
            for (int dt = 0; dt < 4; dt++)
                O[((size_t)(b * LT + qrow) << 9) + h * 64 + (dt << 4) + l15] = Oacc[dt][r] * inv;
        }
    }
}

// ---------------- x = (t + s + x)/3
__global__ __launch_bounds__(256)
void add3_kernel(const float* __restrict__ T, const float* __restrict__ S,
                 float* __restrict__ X){
    size_t idx = (size_t)blockIdx.x * 256 + threadIdx.x;
    X[idx] = (T[idx] + S[idx] + X[idx]) * (1.f / 3.f);
}

extern "C" void kernel_launch(void* const* d_in, const int* in_sizes, int n_in,
                              void* d_out, int out_size, void* d_ws, size_t ws_size,
                              hipStream_t stream)
{
    const float* x_enc   = (const float*)d_in[0];
    const float* down_W  = (const float*)d_in[1];
    const float* down_b  = (const float*)d_in[2];
    const float* conv_W  = (const float*)d_in[3];
    const float* conv_b  = (const float*)d_in[4];
    const float* up_W    = (const float*)d_in[5];
    const float* up_b    = (const float*)d_in[6];
    const float* bc_g    = (const float*)d_in[7];
    const float* bc_b    = (const float*)d_in[8];
    const float* aWq     = (const float*)d_in[9];
    const float* aWk     = (const float*)d_in[10];
    const float* aWv     = (const float*)d_in[11];
    const float* afcW    = (const float*)d_in[12];
    const float* afcb    = (const float*)d_in[13];
    const float* alng    = (const float*)d_in[14];
    const float* alnb    = (const float*)d_in[15];
    const float* fW1     = (const float*)d_in[16];
    const float* fb1     = (const float*)d_in[17];
    const float* fW2     = (const float*)d_in[18];
    const float* fb2     = (const float*)d_in[19];
    const float* flng    = (const float*)d_in[20];
    const float* flnb    = (const float*)d_in[21];

    const size_t NBL = (size_t)BB * LT * 512;
    float* X   = (float*)d_ws;
    float* TMP = X   + NBL;
    float* Qb  = TMP + NBL;
    float* Kb  = Qb  + NBL;
    float* Vb  = Kb  + NBL;
    float* AO  = Vb  + NBL;
    float* TO  = AO  + NBL;
    float* SO  = TO  + NBL;
    uint8_t* SM = (uint8_t*)(SO + NBL);
    int* TIDX = (int*)(SM + (size_t)BB * LT * LT);
    int* TCNT = TIDX + (size_t)LT * 12;
    ushort* WG = (ushort*)(TCNT + LT);
    const size_t M512 = 262144;
    ushort* WdownT = WG;                 size_t wo = M512;
    ushort* WupT   = WG + wo;            wo += M512;
    ushort* WqT    = WG + wo;            wo += 4 * M512;
    ushort* WkT    = WG + wo;            wo += 4 * M512;
    ushort* WvT    = WG + wo;            wo += 4 * M512;
    ushort* WfT    = WG + wo;            wo += 4 * M512;
    ushort* W1T    = WG + wo;            wo += 2 * M512;
    ushort* W2T    = WG + wo;            wo += 2 * M512;
    ushort* WCt    = WG + wo;            wo += 3 * 1048576;
    size_t need = 8 * NBL * sizeof(float) + (size_t)BB * LT * LT
                + (size_t)LT * 13 * 4 + wo * sizeof(ushort);
    if (ws_size < need) return;

    // aliases (lifetimes disjoint)
    float* Y    = Qb;
    float* C1   = Kb;
    float* C2   = C1 + (size_t)BB*256*512;
    float* C3   = C2 + (size_t)BB*64*512;
    float* PCAT = Vb;
    float* XN   = AO;
    float* SIMB = Qb;
    float* Hf   = Qb;
    ushort* QbH = (ushort*)Qb;
    ushort* KbH = (ushort*)Kb;
    ushort* VtH = (ushort*)Vb;

    auto gemmB = [&](const float* A, const ushort* Bw, const float* bias,
                     const float* res, void* C, int M, int K,
                     int act, int omode, int mpb, int orpb, int ooff){
        dim3 grid(8, M / 64);
        gemm_bf16<<<grid, 256, 0, stream>>>(A, Bw, bias, res, C, M, 512, K,
                                            act, omode, mpb, orpb, ooff);
    };

    build_tidx<<<(LT + 255) / 256, 256, 0, stream>>>(TIDX, TCNT);
    // weight repack (every call — inputs restored by harness)
    wtrans<<<dim3(8, 8, 1), 256, 0, stream>>>(down_W, WdownT, 512, 512);
    wtrans<<<dim3(8, 8, 1), 256, 0, stream>>>(up_W,   WupT,   512, 512);
    wtrans<<<dim3(8, 8, 4), 256, 0, stream>>>(aWq,  WqT, 512, 512);
    wtrans<<<dim3(8, 8, 4), 256, 0, stream>>>(aWk,  WkT, 512, 512);
    wtrans<<<dim3(8, 8, 4), 256, 0, stream>>>(aWv,  WvT, 512, 512);
    wtrans<<<dim3(8, 8, 4), 256, 0, stream>>>(afcW, WfT, 512, 512);
    wtrans<<<dim3(8, 8, 2), 256, 0, stream>>>(fW1,  W1T, 512, 512);
    wtrans<<<dim3(8, 8, 2), 256, 0, stream>>>(fW2,  W2T, 512, 512);
    wconv<<<dim3(4096, 3), 256, 0, stream>>>(conv_W, WCt);

    // ---- bottleneck
    gemmB(x_enc, WdownT, down_b, nullptr, Y, BB*1024, 512, 0, 0, 0, 0, 0);
    gemmB(Y,  WCt,             conv_b + 0,    nullptr, C1, BB*256, 2048, 1, 0, 0, 0, 0);
    gemmB(C1, WCt + 1048576,   conv_b + 512,  nullptr, C2, BB*64,  2048, 1, 0, 0, 0, 0);
    gemmB(C2, WCt + 2*1048576, conv_b + 1024, nullptr, C3, BB*16,  2048, 1, 0, 0, 0, 0);
    pcat_copy<<<(BB*336*512)/256, 256, 0, stream>>>(C1, C2, C3, PCAT);
    gemmB(PCAT, WupT, up_b, nullptr, TMP, BB*336, 512, 0, 0, 336, LT, 1024);
    xenc_copy<<<(BB*1024*512)/256, 256, 0, stream>>>(x_enc, TMP);
    ln_kernel<<<(BB*LT)/4, 256, 0, stream>>>(TMP, bc_g, bc_b, X, 1e-5f);

    // ---- transformer layers
    for (int l = 0; l < 2; l++){
        hipMemsetAsync(SM, 0, (size_t)BB * LT * LT, stream);
        rownorm_kernel<<<(BB*LT)/4, 256, 0, stream>>>(X, XN);
        sim_gemm<<<dim3(274, BB), 256, 0, stream>>>(XN, SIMB);
        topk_sel<<<BB*LT, 256, 0, stream>>>(SIMB, SM);

        for (int j = 0; j < 2; j++){
            int li = l * 2 + j;
            const float* bf = afcb + (size_t)li * 512;
            const float* lg = alng + (size_t)li * 512;
            const float* lb = alnb + (size_t)li * 512;
            gemmB(X, WqT + (size_t)li * M512, nullptr, nullptr, QbH, BB*LT, 512, 0, 1, 0, 0, 0);
            gemmB(X, WkT + (size_t)li * M512, nullptr, nullptr, KbH, BB*LT, 512, 0, 1, 0, 0, 0);
            gemmB(X, WvT + (size_t)li * M512, nullptr, nullptr, VtH, BB*LT, 512, 0, 2, 0, 0, 0);
            if (j == 0)
                attn_sparse<<<(BB*NHH*LT)/4, 256, 0, stream>>>(QbH, KbH, VtH, TIDX, TCNT, AO);
            else
                flash_mfma<<<dim3(22, 32), 256, 0, stream>>>(QbH, KbH, VtH, SM, AO);
            gemmB(AO, WfT + (size_t)li * M512, bf, X, TMP, BB*LT, 512, 0, 0, 0, 0, 0);
            ln_kernel<<<(BB*LT)/4, 256, 0, stream>>>(TMP, lg, lb, (j == 0) ? TO : SO, 1e-6f);
        }
        add3_kernel<<<(int)(NBL/256), 256, 0, stream>>>(TO, SO, X);

        // FFN
        gemmB(X,  W1T + (size_t)l * M512, fb1 + (size_t)l*512, nullptr, Hf, BB*LT, 512, 2, 0, 0, 0, 0);
        gemmB(Hf, W2T + (size_t)l * M512, fb2 + (size_t)l*512, X, TMP, BB*LT, 512, 0, 0, 0, 0, 0);
        ln_kernel<<<(BB*LT)/4, 256, 0, stream>>>(TMP, flng + (size_t)l*512, flnb + (size_t)l*512,
                                                 (l == 1) ? (float*)d_out : X, 1e-6f);
    }
}

// Round 6
// 1289.349 us; speedup vs baseline: 3.5748x; 1.1932x over previous
//
#include <hip/hip_runtime.h>
#include <float.h>
#include <math.h>
#include <stdint.h>

#define LT 1360
#define BB 4
#define DM 512
#define NHH 8
#define NBLE 2785280   // BB*LT*512 elements

typedef __attribute__((ext_vector_type(8))) short short8;
typedef __attribute__((ext_vector_type(4))) float f32x4;

__device__ __forceinline__ ushort f2b(float x){
    uint32_t u = __float_as_uint(x);
    return (ushort)((u + 0x7fffu + ((u >> 16) & 1u)) >> 16);
}
__device__ __forceinline__ float b2f(ushort u){
    return __uint_as_float(((uint32_t)u) << 16);
}

// semantic sim buffer layout (per batch)
#define SG0 0
#define SG1 1048576
#define SG2 (SG1 + 65536)
#define SG3 (SG2 + 4096)
#define SBT (SG3 + 256)

__device__ __forceinline__ void blk_info(int i, int& bi, int& st, int& n){
    if (i < 1024){ bi = 0; st = 0;    n = 1024; }
    else if (i < 1280){ bi = 1; st = 1024; n = 256; }
    else if (i < 1344){ bi = 2; st = 1280; n = 64; }
    else { bi = 3; st = 1344; n = 16; }
}

// ---------------- temporal allowed-index lists
__global__ __launch_bounds__(256)
void build_tidx(int* __restrict__ idx, int* __restrict__ cnt){
    int i = blockIdx.x * 256 + threadIdx.x;
    if (i >= LT) return;
    int bi, st, n; blk_info(i, bi, st, n);
    int c = 0; int* row = idx + i * 12;
    int lo = (i - 2 > st) ? i - 2 : st;
    int hi = (i + 2 < st + n - 1) ? i + 2 : st + n - 1;
    for (int j = lo; j <= hi; j++) row[c++] = j;
    if (bi < 3) row[c++] = st + n + (i - st) / 4;
    if (bi > 0){
        int stc = st - n * 4;
        int base = stc + (i - st) * 4;
        for (int t = 0; t < 4; t++) row[c++] = base + t;
    }
    cnt[i] = c;
}

// ---------------- weight transpose+cast: Wd[n*K+k] = bf16(Ws[k*N+n]); dst stride per matrix
__global__ __launch_bounds__(256)
void wtrans(const float* __restrict__ W, ushort* __restrict__ Wt, int K, int N, long dstStride){
    int mat = blockIdx.z;
    const float* Ws = W + (size_t)mat * K * N;
    ushort* Wd = Wt + (size_t)mat * dstStride;
    int k0 = blockIdx.y << 6, n0 = blockIdx.x << 6;
    __shared__ ushort t[64][72];
    int tid = threadIdx.x;
    #pragma unroll
    for (int p = 0; p < 4; p++){
        int idx = tid + (p << 8);
        int r = idx >> 4, c4 = (idx & 15) << 2;
        float4 v = *(const float4*)(Ws + (size_t)(k0 + r) * N + n0 + c4);
        t[c4+0][r] = f2b(v.x); t[c4+1][r] = f2b(v.y);
        t[c4+2][r] = f2b(v.z); t[c4+3][r] = f2b(v.w);
    }
    __syncthreads();
    #pragma unroll
    for (int p = 0; p < 4; p++){
        int idx = tid + (p << 8);
        int r = idx >> 4, c4 = (idx & 15) << 2;
        *(uint2*)&Wd[(size_t)(n0 + r) * K + k0 + c4] = *(uint2*)&t[r][c4];
    }
}

// ---------------- conv weight repack+cast
__global__ __launch_bounds__(256)
void wconv(const float* __restrict__ cw, ushort* __restrict__ wt){
    int conv = blockIdx.y;
    const float* src = cw + (size_t)conv * 512 * 512 * 4;
    ushort* dst = wt + (size_t)conv * 2048 * 512;
    int idx = blockIdx.x * 256 + threadIdx.x;
    int o = idx >> 11, rest = idx & 2047;
    int k = rest >> 9, ii = rest & 511;
    dst[idx] = f2b(src[((size_t)(o << 9) + ii) * 4 + k]);
}

// ---------------- bf16 MFMA GEMM, 64x64 tile, BK=32, 256 thr / 4 waves
// act: 0 none, 1 ELU(cscale*v), 2 relu
// omode: 0 f32 out (+row remap), 1 bf16 out, 2 bf16 V^T out, 3 fused QKV out (N=1536)
__global__ __launch_bounds__(256)
void gemm_bf16(const float* __restrict__ A, const ushort* __restrict__ Bw,
               const float* __restrict__ bias, const float* __restrict__ Rres,
               void* __restrict__ Cout, int M, int N, int K,
               int act, int omode, int mpb, int orpb, int ooff)
{
    __shared__ ushort As[64][40];
    __shared__ ushort Bs[64][40];
    int tid = threadIdx.x;
    int lane = tid & 63, w = tid >> 6, quad = lane >> 4, l15 = lane & 15;
    int gm = blockIdx.y << 6, gn = blockIdx.x << 6;
    int wr = (w >> 1) << 5, wc = (w & 1) << 5;
    int srow = tid >> 2, sc8 = (tid & 3) << 3;
    f32x4 acc[2][2] = {{{0.f,0.f,0.f,0.f},{0.f,0.f,0.f,0.f}},{{0.f,0.f,0.f,0.f},{0.f,0.f,0.f,0.f}}};
    const float* Arow = A + (size_t)(gm + srow) * K;
    const ushort* Brow = Bw + (size_t)(gn + srow) * K;
    for (int k0 = 0; k0 < K; k0 += 32){
        float4 a0 = *(const float4*)(Arow + k0 + sc8);
        float4 a1 = *(const float4*)(Arow + k0 + sc8 + 4);
        uint4 av;
        av.x = (uint32_t)f2b(a0.x) | ((uint32_t)f2b(a0.y) << 16);
        av.y = (uint32_t)f2b(a0.z) | ((uint32_t)f2b(a0.w) << 16);
        av.z = (uint32_t)f2b(a1.x) | ((uint32_t)f2b(a1.y) << 16);
        av.w = (uint32_t)f2b(a1.z) | ((uint32_t)f2b(a1.w) << 16);
        *(uint4*)&As[srow][sc8] = av;
        *(uint4*)&Bs[srow][sc8] = *(const uint4*)(Brow + k0 + sc8);
        __syncthreads();
        short8 af0 = *(const short8*)&As[wr + l15][quad << 3];
        short8 af1 = *(const short8*)&As[wr + 16 + l15][quad << 3];
        short8 bf0 = *(const short8*)&Bs[wc + l15][quad << 3];
        short8 bf1 = *(const short8*)&Bs[wc + 16 + l15][quad << 3];
        acc[0][0] = __builtin_amdgcn_mfma_f32_16x16x32_bf16(af0, bf0, acc[0][0], 0, 0, 0);
        acc[0][1] = __builtin_amdgcn_mfma_f32_16x16x32_bf16(af0, bf1, acc[0][1], 0, 0, 0);
        acc[1][0] = __builtin_amdgcn_mfma_f32_16x16x32_bf16(af1, bf0, acc[1][0], 0, 0, 0);
        acc[1][1] = __builtin_amdgcn_mfma_f32_16x16x32_bf16(af1, bf1, acc[1][1], 0, 0, 0);
        __syncthreads();
    }
    const float cscale = 0.9999950000375f;
    #pragma unroll
    for (int mi = 0; mi < 2; mi++){
        #pragma unroll
        for (int r = 0; r < 4; r++){
            int row = gm + wr + (mi << 4) + (quad << 2) + r;
            #pragma unroll
            for (int ni = 0; ni < 2; ni++){
                int col = gn + wc + (ni << 4) + l15;
                float v = acc[mi][ni][r];
                if (bias) v += bias[col];
                if (Rres) v += Rres[(size_t)row * N + col];
                if (act == 1){ v *= cscale; v = (v > 0.f) ? v : expm1f(v); }
                else if (act == 2){ v = fmaxf(v, 0.f); }
                if (omode == 0){
                    int orow = mpb ? (row / mpb) * orpb + ooff + (row % mpb) : row;
                    ((float*)Cout)[(size_t)orow * N + col] = v;
                } else if (omode == 1){
                    ((ushort*)Cout)[(size_t)row * N + col] = f2b(v);
                } else if (omode == 2){
                    int bb = row / LT, ii = row - bb * LT;
                    ((ushort*)Cout)[((size_t)(bb * 512 + col)) * LT + ii] = f2b(v);
                } else {
                    int seg = col >> 9, c5 = col & 511;
                    ushort* Ob = (ushort*)Cout;
                    if (seg == 0)      Ob[(size_t)row * 512 + c5] = f2b(v);
                    else if (seg == 1) Ob[(size_t)2*NBLE + (size_t)row * 512 + c5] = f2b(v);
                    else {
                        int bb = row / LT, ii = row - bb * LT;
                        Ob[(size_t)4*NBLE + ((size_t)(bb * 512 + c5)) * LT + ii] = f2b(v);
                    }
                }
            }
        }
    }
}

// ---------------- semantic sim via split-bf16 MFMA: sim = hi·hi^T + hi·lo^T + lo·hi^T
__global__ __launch_bounds__(256)
void sim_mfma(const float* __restrict__ XN, float* __restrict__ SIM){
    __shared__ ushort Ah[64][40], Al[64][40], Bh[64][40], Bl[64][40];
    int x = blockIdx.x, b = blockIdx.y;
    int ti, tj, st, n, goff;
    if (x < 256){ ti = x >> 4; tj = x & 15; st = 0; n = 1024; goff = SG0; }
    else if (x < 272){ int y = x - 256; ti = y >> 2; tj = y & 3; st = 1024; n = 256; goff = SG1; }
    else if (x == 272){ ti = 0; tj = 0; st = 1280; n = 64; goff = SG2; }
    else { ti = 0; tj = 0; st = 1344; n = 16; goff = SG3; }
    const float* Xb = XN + (((size_t)b * LT + st) << 9);
    float* Cb = SIM + (size_t)b * SBT + goff;
    int gm = ti << 6, gn = tj << 6;
    int tid = threadIdx.x;
    int lane = tid & 63, w = tid >> 6, quad = lane >> 4, l15 = lane & 15;
    int wr = (w >> 1) << 5, wc = (w & 1) << 5;
    int srow = tid >> 2, sc8 = (tid & 3) << 3;
    int ra = gm + srow; if (ra > n - 1) ra = n - 1;
    int rb = gn + srow; if (rb > n - 1) rb = n - 1;
    f32x4 acc[2][2] = {{{0.f,0.f,0.f,0.f},{0.f,0.f,0.f,0.f}},{{0.f,0.f,0.f,0.f},{0.f,0.f,0.f,0.f}}};
    for (int k0 = 0; k0 < 512; k0 += 32){
        float av8[8], bv8[8];
        *(float4*)&av8[0] = *(const float4*)(Xb + ((size_t)ra << 9) + k0 + sc8);
        *(float4*)&av8[4] = *(const float4*)(Xb + ((size_t)ra << 9) + k0 + sc8 + 4);
        *(float4*)&bv8[0] = *(const float4*)(Xb + ((size_t)rb << 9) + k0 + sc8);
        *(float4*)&bv8[4] = *(const float4*)(Xb + ((size_t)rb << 9) + k0 + sc8 + 4);
        ushort ah[8], al[8], bh[8], bl[8];
        #pragma unroll
        for (int t = 0; t < 8; t++){
            ah[t] = f2b(av8[t]); al[t] = f2b(av8[t] - b2f(ah[t]));
            bh[t] = f2b(bv8[t]); bl[t] = f2b(bv8[t] - b2f(bh[t]));
        }
        uint4 u;
        u.x = (uint32_t)ah[0]|((uint32_t)ah[1]<<16); u.y = (uint32_t)ah[2]|((uint32_t)ah[3]<<16);
        u.z = (uint32_t)ah[4]|((uint32_t)ah[5]<<16); u.w = (uint32_t)ah[6]|((uint32_t)ah[7]<<16);
        *(uint4*)&Ah[srow][sc8] = u;
        u.x = (uint32_t)al[0]|((uint32_t)al[1]<<16); u.y = (uint32_t)al[2]|((uint32_t)al[3]<<16);
        u.z = (uint32_t)al[4]|((uint32_t)al[5]<<16); u.w = (uint32_t)al[6]|((uint32_t)al[7]<<16);
        *(uint4*)&Al[srow][sc8] = u;
        u.x = (uint32_t)bh[0]|((uint32_t)bh[1]<<16); u.y = (uint32_t)bh[2]|((uint32_t)bh[3]<<16);
        u.z = (uint32_t)bh[4]|((uint32_t)bh[5]<<16); u.w = (uint32_t)bh[6]|((uint32_t)bh[7]<<16);
        *(uint4*)&Bh[srow][sc8] = u;
        u.x = (uint32_t)bl[0]|((uint32_t)bl[1]<<16); u.y = (uint32_t)bl[2]|((uint32_t)bl[3]<<16);
        u.z = (uint32_t)bl[4]|((uint32_t)bl[5]<<16); u.w = (uint32_t)bl[6]|((uint32_t)bl[7]<<16);
        *(uint4*)&Bl[srow][sc8] = u;
        __syncthreads();
        short8 ah0 = *(const short8*)&Ah[wr + l15][quad << 3];
        short8 ah1 = *(const short8*)&Ah[wr + 16 + l15][quad << 3];
        short8 al0 = *(const short8*)&Al[wr + l15][quad << 3];
        short8 al1 = *(const short8*)&Al[wr + 16 + l15][quad << 3];
        short8 bh0 = *(const short8*)&Bh[wc + l15][quad << 3];
        short8 bh1 = *(const short8*)&Bh[wc + 16 + l15][quad << 3];
        short8 bl0 = *(const short8*)&Bl[wc + l15][quad << 3];
        short8 bl1 = *(const short8*)&Bl[wc + 16 + l15][quad << 3];
        acc[0][0] = __builtin_amdgcn_mfma_f32_16x16x32_bf16(ah0, bh0, acc[0][0], 0, 0, 0);
        acc[0][0] = __builtin_amdgcn_mfma_f32_16x16x32_bf16(ah0, bl0, acc[0][0], 0, 0, 0);
        acc[0][0] = __builtin_amdgcn_mfma_f32_16x16x32_bf16(al0, bh0, acc[0][0], 0, 0, 0);
        acc[0][1] = __builtin_amdgcn_mfma_f32_16x16x32_bf16(ah0, bh1, acc[0][1], 0, 0, 0);
        acc[0][1] = __builtin_amdgcn_mfma_f32_16x16x32_bf16(ah0, bl1, acc[0][1], 0, 0, 0);
        acc[0][1] = __builtin_amdgcn_mfma_f32_16x16x32_bf16(al0, bh1, acc[0][1], 0, 0, 0);
        acc[1][0] = __builtin_amdgcn_mfma_f32_16x16x32_bf16(ah1, bh0, acc[1][0], 0, 0, 0);
        acc[1][0] = __builtin_amdgcn_mfma_f32_16x16x32_bf16(ah1, bl0, acc[1][0], 0, 0, 0);
        acc[1][0] = __builtin_amdgcn_mfma_f32_16x16x32_bf16(al1, bh0, acc[1][0], 0, 0, 0);
        acc[1][1] = __builtin_amdgcn_mfma_f32_16x16x32_bf16(ah1, bh1, acc[1][1], 0, 0, 0);
        acc[1][1] = __builtin_amdgcn_mfma_f32_16x16x32_bf16(ah1, bl1, acc[1][1], 0, 0, 0);
        acc[1][1] = __builtin_amdgcn_mfma_f32_16x16x32_bf16(al1, bh1, acc[1][1], 0, 0, 0);
        __syncthreads();
    }
    #pragma unroll
    for (int mi = 0; mi < 2; mi++){
        #pragma unroll
        for (int r = 0; r < 4; r++){
            int row = gm + wr + (mi << 4) + (quad << 2) + r;
            if (row < n){
                #pragma unroll
                for (int ni = 0; ni < 2; ni++){
                    int col = gn + wc + (ni << 4) + l15;
                    if (col < n) Cb[(size_t)row * n + col] = acc[mi][ni][r];
                }
            }
        }
    }
}

// ---------------- concat conv pyramids
__global__ __launch_bounds__(256)
void pcat_copy(const float* __restrict__ C1, const float* __restrict__ C2,
               const float* __restrict__ C3, float* __restrict__ PC){
    int idx = blockIdx.x * 256 + threadIdx.x;
    int d = idx & 511;
    int r = (idx >> 9) % 336;
    int b = idx / (336 * 512);
    float v;
    if (r < 256)       v = C1[(((size_t)b * 256 + r) << 9) + d];
    else if (r < 320)  v = C2[(((size_t)b * 64 + (r - 256)) << 9) + d];
    else               v = C3[(((size_t)b * 16 + (r - 320)) << 9) + d];
    PC[idx] = v;
}

__global__ __launch_bounds__(256)
void xenc_copy(const float* __restrict__ xe, float* __restrict__ dst){
    int idx = blockIdx.x * 256 + threadIdx.x;
    int d = idx & 511;
    int l = (idx >> 9) & 1023;
    int b = idx >> 19;
    dst[(((size_t)b * LT + l) << 9) + d] = xe[idx];
}

// ---------------- LayerNorm over 512, wave per row
__global__ __launch_bounds__(256)
void ln_kernel(const float* __restrict__ in, const float* __restrict__ g,
               const float* __restrict__ bta, float* __restrict__ out, float eps){
    int wid = threadIdx.x >> 6, lane = threadIdx.x & 63;
    int row = blockIdx.x * 4 + wid;
    const float* p = in + ((size_t)row << 9);
    float vals[8]; float s = 0.f, s2 = 0.f;
    #pragma unroll
    for (int t = 0; t < 8; t++){
        float v = p[lane + t * 64]; vals[t] = v; s += v; s2 += v * v;
    }
    #pragma unroll
    for (int off = 32; off; off >>= 1){
        s  += __shfl_xor(s,  off, 64);
        s2 += __shfl_xor(s2, off, 64);
    }
    float mu = s * (1.f / 512.f);
    float var = s2 * (1.f / 512.f) - mu * mu;
    float r = rsqrtf(var + eps);
    float* q = out + ((size_t)row << 9);
    #pragma unroll
    for (int t = 0; t < 8; t++){
        int c = lane + t * 64;
        q[c] = (vals[t] - mu) * r * g[c] + bta[c];
    }
}

__global__ __launch_bounds__(256)
void rownorm_kernel(const float* __restrict__ in, float* __restrict__ out){
    int wid = threadIdx.x >> 6, lane = threadIdx.x & 63;
    int row = blockIdx.x * 4 + wid;
    const float* p = in + ((size_t)row << 9);
    float vals[8]; float s2 = 0.f;
    #pragma unroll
    for (int t = 0; t < 8; t++){
        float v = p[lane + t * 64]; vals[t] = v; s2 += v * v;
    }
    #pragma unroll
    for (int off = 32; off; off >>= 1) s2 += __shfl_xor(s2, off, 64);
    float inv = 1.f / fmaxf(sqrtf(s2), 1e-8f);
    float* q = out + ((size_t)row << 9);
    #pragma unroll
    for (int t = 0; t < 8; t++) q[lane + t * 64] = vals[t] * inv;
}

// ---------------- top-k radix select (fp32)
__device__ __forceinline__ uint32_t mono_key(float v){
    uint32_t b = __float_as_uint(v);
    return b ^ ((b & 0x80000000u) ? 0xFFFFFFFFu : 0x80000000u);
}

__global__ __launch_bounds__(256)
void topk_sel(const float* __restrict__ SIM, uint8_t* __restrict__ SM){
    __shared__ float sim[1024];
    __shared__ uint32_t hist[256];
    __shared__ int lidx[1024];
    __shared__ int scal[3];
    int r = blockIdx.x;
    int b = r / LT, i = r % LT;
    int bi, st, n; blk_info(i, bi, st, n);
    int goff = (bi == 0) ? SG0 : (bi == 1) ? SG1 : (bi == 2) ? SG2 : SG3;
    int tid = threadIdx.x;
    const float* srow = SIM + (size_t)b * SBT + goff + (size_t)(i - st) * n;
    hist[tid] = 0;
    if (tid == 0) scal[2] = 0;
    __syncthreads();
    for (int j4 = tid << 2; j4 < n; j4 += 1024){
        float4 v4 = *(const float4*)(srow + j4);
        *(float4*)&sim[j4] = v4;
        atomicAdd(&hist[mono_key(v4.x) >> 24], 1u);
        atomicAdd(&hist[mono_key(v4.y) >> 24], 1u);
        atomicAdd(&hist[mono_key(v4.z) >> 24], 1u);
        atomicAdd(&hist[mono_key(v4.w) >> 24], 1u);
    }
    __syncthreads();
    #pragma unroll
    for (int off = 1; off < 256; off <<= 1){
        uint32_t add = (tid + off < 256) ? hist[tid + off] : 0u;
        __syncthreads();
        hist[tid] += add;
        __syncthreads();
    }
    int k = (n < 32) ? n : 32;
    uint32_t ge = hist[tid];
    uint32_t gt = (tid < 255) ? hist[tid + 1] : 0u;
    if (ge >= (uint32_t)k && gt < (uint32_t)k){ scal[0] = tid; scal[1] = (int)gt; }
    __syncthreads();
    int Bcut = scal[0], C1 = scal[1];
    int R = k - C1;
    uint8_t* mrow = SM + ((size_t)b * LT + i) * LT + st;
    for (int j = tid; j < n; j += 256){
        int bin = (int)(mono_key(sim[j]) >> 24);
        if (bin > Bcut) mrow[j] = 1;
        else if (bin == Bcut){ int p = atomicAdd(&scal[2], 1); lidx[p] = j; }
    }
    __syncthreads();
    int cb = scal[2];
    for (int it = 0; it < R; it++){
        if (tid < 64){
            float bv = -FLT_MAX; int bj = 1 << 30;
            for (int p = tid; p < cb; p += 64){
                int j = lidx[p]; float v = sim[j];
                if (v > bv || (v == bv && j < bj)){ bv = v; bj = j; }
            }
            #pragma unroll
            for (int off = 32; off; off >>= 1){
                float ov = __shfl_xor(bv, off, 64);
                int   oj = __shfl_xor(bj, off, 64);
                if (ov > bv || (ov == bv && oj < bj)){ bv = ov; bj = oj; }
            }
            if (tid == 0){ mrow[bj] = 1; sim[bj] = -FLT_MAX; }
        }
        __syncthreads();
    }
}

// ---------------- sparse temporal attention (bf16 inputs, V transposed)
__global__ __launch_bounds__(256)
void attn_sparse(const ushort* __restrict__ Q, const ushort* __restrict__ Kp,
                 const ushort* __restrict__ Vt, const int* __restrict__ IDX,
                 const int* __restrict__ CNT, float* __restrict__ O){
    int wid = threadIdx.x >> 6, lane = threadIdx.x & 63;
    int row = blockIdx.x * 4 + wid;
    int b = row / (NHH * LT);
    int rem = row % (NHH * LT);
    int h = rem / LT, i = rem % LT;
    int c = CNT[i];
    int jl = IDX[i * 12 + (lane % 12)];
    float qd = b2f(Q[(((size_t)b * LT + i) << 9) + h * 64 + lane]);
    const ushort* kb = Kp + (((size_t)b * LT) << 9) + h * 64 + lane;
    const ushort* vb = Vt + ((size_t)(b * 512 + h * 64 + lane)) * LT;
    float m = -FLT_MAX, lsum = 0.f, o = 0.f;
    for (int t = 0; t < c; t++){
        int j = __shfl(jl, t, 64);
        float s = qd * b2f(kb[(size_t)j << 9]);
        #pragma unroll
        for (int off = 32; off; off >>= 1) s += __shfl_xor(s, off, 64);
        s *= 0.125f;
        float mn = fmaxf(m, s);
        float sc = __expf(m - mn);
        float p  = __expf(s - mn);
        lsum = lsum * sc + p;
        o = o * sc + p * b2f(vb[j]);
        m = mn;
    }
    O[(((size_t)b * LT + i) << 9) + h * 64 + lane] = o / lsum;
}

// ---------------- MFMA flash attention (semantic, byte mask)
__global__ __launch_bounds__(256)
void flash_mfma(const ushort* __restrict__ Q, const ushort* __restrict__ Kp,
                const ushort* __restrict__ Vt, const uint8_t* __restrict__ Mk,
                float* __restrict__ O)
{
    __shared__ ushort Ks[64][72];
    __shared__ ushort Vs[64][72];
    __shared__ uint8_t Ms[64][64];
    __shared__ ushort Ps[4][16][72];
    int bh = blockIdx.y, b = bh >> 3, h = bh & 7;
    int q0 = blockIdx.x << 6;
    int tid = threadIdx.x;
    int w = tid >> 6, lane = tid & 63, quad = lane >> 4, l15 = lane & 15;

    int qm = q0 + w * 16 + l15;
    int qmc = (qm < LT) ? qm : (LT - 1);
    const ushort* qp = Q + ((size_t)(b * LT + qmc) << 9) + h * 64 + (quad << 3);
    short8 qf0 = *(const short8*)qp;
    short8 qf1 = *(const short8*)(qp + 32);

    float m_i[4] = {-FLT_MAX, -FLT_MAX, -FLT_MAX, -FLT_MAX};
    float l_i[4] = {0.f, 0.f, 0.f, 0.f};
    f32x4 Oacc[4] = {{0.f,0.f,0.f,0.f},{0.f,0.f,0.f,0.f},{0.f,0.f,0.f,0.f},{0.f,0.f,0.f,0.f}};

    int srow = tid >> 2, sc = (tid & 3) << 4;
    const uint8_t* Mbase = Mk + (size_t)b * LT * LT;

    for (int kt = 0; kt < 22; kt++){
        int k0 = kt << 6;
        __syncthreads();
        {
            int krow = k0 + srow; if (krow >= LT) krow = LT - 1;
            const ushort* kp = Kp + ((size_t)(b * LT + krow) << 9) + h * 64 + sc;
            *(uint4*)&Ks[srow][sc]     = *(const uint4*)kp;
            *(uint4*)&Ks[srow][sc + 8] = *(const uint4*)(kp + 8);
            int kbase = k0 + sc; if (kbase > LT - 16) kbase = LT - 16;
            const ushort* vp = Vt + ((size_t)(b * 512 + h * 64 + srow)) * LT + kbase;
            *(uint4*)&Vs[srow][sc]     = *(const uint4*)vp;
            *(uint4*)&Vs[srow][sc + 8] = *(const uint4*)(vp + 8);
            int mrow = q0 + srow; if (mrow >= LT) mrow = LT - 1;
            *(uint4*)&Ms[srow][sc] = *(const uint4*)(Mbase + (size_t)mrow * LT + k0 + sc);
        }
        __syncthreads();
        f32x4 s[4] = {{0.f,0.f,0.f,0.f},{0.f,0.f,0.f,0.f},{0.f,0.f,0.f,0.f},{0.f,0.f,0.f,0.f}};
        #pragma unroll
        for (int nt = 0; nt < 4; nt++){
            short8 kf0 = *(const short8*)&Ks[(nt << 4) + l15][quad << 3];
            short8 kf1 = *(const short8*)&Ks[(nt << 4) + l15][32 + (quad << 3)];
            s[nt] = __builtin_amdgcn_mfma_f32_16x16x32_bf16(qf0, kf0, s[nt], 0, 0, 0);
            s[nt] = __builtin_amdgcn_mfma_f32_16x16x32_bf16(qf1, kf1, s[nt], 0, 0, 0);
        }
        float alpha[4];
        #pragma unroll
        for (int r = 0; r < 4; r++){
            int lrow = (w << 4) + (quad << 2) + r;
            float sv[4]; bool bad[4];
            #pragma unroll
            for (int nt = 0; nt < 4; nt++){
                int kcol = k0 + (nt << 4) + l15;
                uint32_t mw = *(const uint32_t*)&Ms[lrow][(nt << 4) + (l15 & ~3)];
                uint8_t mb = (uint8_t)(mw >> ((l15 & 3) << 3));
                bad[nt] = (mb != 0) || (kcol >= LT);
                sv[nt] = s[nt][r] * 0.125f;
            }
            float tmax = -FLT_MAX;
            #pragma unroll
            for (int nt = 0; nt < 4; nt++) if (!bad[nt]) tmax = fmaxf(tmax, sv[nt]);
            #pragma unroll
            for (int off = 1; off < 16; off <<= 1) tmax = fmaxf(tmax, __shfl_xor(tmax, off, 64));
            float mn = fmaxf(m_i[r], tmax);
            alpha[r] = __expf(m_i[r] - mn);
            float psum = 0.f;
            float pv[4];
            #pragma unroll
            for (int nt = 0; nt < 4; nt++){
                pv[nt] = bad[nt] ? 0.f : __expf(sv[nt] - mn);
                psum += pv[nt];
            }
            #pragma unroll
            for (int off = 1; off < 16; off <<= 1) psum += __shfl_xor(psum, off, 64);
            l_i[r] = l_i[r] * alpha[r] + psum;
            m_i[r] = mn;
            #pragma unroll
            for (int nt = 0; nt < 4; nt++)
                Ps[w][(quad << 2) + r][(nt << 4) + l15] = f2b(pv[nt]);
        }
        #pragma unroll
        for (int dt = 0; dt < 4; dt++)
            #pragma unroll
            for (int r = 0; r < 4; r++)
                Oacc[dt][r] *= alpha[r];
        short8 pf0 = *(const short8*)&Ps[w][l15][quad << 3];
        short8 pf1 = *(const short8*)&Ps[w][l15][32 + (quad << 3)];
        #pragma unroll
        for (int dt = 0; dt < 4; dt++){
            short8 vf0 = *(const short8*)&Vs[(dt << 4) + l15][quad << 3];
            short8 vf1 = *(const short8*)&Vs[(dt << 4) + l15][32 + (quad << 3)];
            Oacc[dt] = __builtin_amdgcn_mfma_f32_16x16x32_bf16(pf0, vf0, Oacc[dt], 0, 0, 0);
            Oacc[dt] = __builtin_amdgcn_mfma_f32_16x16x32_bf16(pf1, vf1, Oacc[dt], 0, 0, 0);
        }
    }
    #pragma unroll
    for (int r = 0; r < 4; r++){
        int qrow = q0 + (w << 4) + (quad << 2) + r;
        if (qrow < LT){
            float inv = 1.f / l_i[r];
            #pragma unroll
            for (int dt = 0; dt < 4; dt++)
                O[((size_t)(b * LT + qrow) << 9) + h * 64 + (dt << 4) + l15] = Oacc[dt][r] * inv;
        }
    }
}

// ---------------- x = (t + s + x)/3
__global__ __launch_bounds__(256)
void add3_kernel(const float* __restrict__ T, const float* __restrict__ S,
                 float* __restrict__ X){
    size_t idx = (size_t)blockIdx.x * 256 + threadIdx.x;
    X[idx] = (T[idx] + S[idx] + X[idx]) * (1.f / 3.f);
}

extern "C" void kernel_launch(void* const* d_in, const int* in_sizes, int n_in,
                              void* d_out, int out_size, void* d_ws, size_t ws_size,
                              hipStream_t stream)
{
    const float* x_enc   = (const float*)d_in[0];
    const float* down_W  = (const float*)d_in[1];
    const float* down_b  = (const float*)d_in[2];
    const float* conv_W  = (const float*)d_in[3];
    const float* conv_b  = (const float*)d_in[4];
    const float* up_W    = (const float*)d_in[5];
    const float* up_b    = (const float*)d_in[6];
    const float* bc_g    = (const float*)d_in[7];
    const float* bc_b    = (const float*)d_in[8];
    const float* aWq     = (const float*)d_in[9];
    const float* aWk     = (const float*)d_in[10];
    const float* aWv     = (const float*)d_in[11];
    const float* afcW    = (const float*)d_in[12];
    const float* afcb    = (const float*)d_in[13];
    const float* alng    = (const float*)d_in[14];
    const float* alnb    = (const float*)d_in[15];
    const float* fW1     = (const float*)d_in[16];
    const float* fb1     = (const float*)d_in[17];
    const float* fW2     = (const float*)d_in[18];
    const float* fb2     = (const float*)d_in[19];
    const float* flng    = (const float*)d_in[20];
    const float* flnb    = (const float*)d_in[21];

    const size_t NBL = (size_t)NBLE;
    float* X   = (float*)d_ws;
    float* TMP = X   + NBL;
    float* Qb  = TMP + NBL;
    float* Kb  = Qb  + NBL;
    float* Vb  = Kb  + NBL;
    float* AO  = Vb  + NBL;
    float* TO  = AO  + NBL;
    float* SO  = TO  + NBL;
    uint8_t* SM = (uint8_t*)(SO + NBL);
    int* TIDX = (int*)(SM + (size_t)BB * LT * LT);
    int* TCNT = TIDX + (size_t)LT * 12;
    ushort* WG = (ushort*)(TCNT + LT);
    const size_t M512 = 262144;
    ushort* WdownT = WG;                 size_t wo = M512;
    ushort* WupT   = WG + wo;            wo += M512;
    ushort* Wqkv   = WG + wo;            wo += 12 * M512;   // 4 layers x [Wq|Wk|Wv]^T
    ushort* WfT    = WG + wo;            wo += 4 * M512;
    ushort* W1T    = WG + wo;            wo += 2 * M512;
    ushort* W2T    = WG + wo;            wo += 2 * M512;
    ushort* WCt    = WG + wo;            wo += 3 * 1048576;
    size_t need = 8 * NBL * sizeof(float) + (size_t)BB * LT * LT
                + (size_t)LT * 13 * 4 + wo * sizeof(ushort);
    if (ws_size < need) return;

    // aliases (lifetimes disjoint)
    float* Y    = Qb;
    float* C1   = Kb;
    float* C2   = C1 + (size_t)BB*256*512;
    float* C3   = C2 + (size_t)BB*64*512;
    float* PCAT = Vb;
    float* XN   = AO;
    float* SIMB = Qb;
    float* Hf   = Qb;
    ushort* QbH = (ushort*)Qb;
    ushort* KbH = (ushort*)Kb;
    ushort* VtH = (ushort*)Vb;

    auto gemmB = [&](const float* A, const ushort* Bw, const float* bias,
                     const float* res, void* C, int M, int N, int K,
                     int act, int omode, int mpb, int orpb, int ooff){
        dim3 grid(N / 64, M / 64);
        gemm_bf16<<<grid, 256, 0, stream>>>(A, Bw, bias, res, C, M, N, K,
                                            act, omode, mpb, orpb, ooff);
    };

    build_tidx<<<(LT + 255) / 256, 256, 0, stream>>>(TIDX, TCNT);
    wtrans<<<dim3(8, 8, 1), 256, 0, stream>>>(down_W, WdownT, 512, 512, M512);
    wtrans<<<dim3(8, 8, 1), 256, 0, stream>>>(up_W,   WupT,   512, 512, M512);
    wtrans<<<dim3(8, 8, 4), 256, 0, stream>>>(aWq,  Wqkv + 0 * M512, 512, 512, 3 * (long)M512);
    wtrans<<<dim3(8, 8, 4), 256, 0, stream>>>(aWk,  Wqkv + 1 * M512, 512, 512, 3 * (long)M512);
    wtrans<<<dim3(8, 8, 4), 256, 0, stream>>>(aWv,  Wqkv + 2 * M512, 512, 512, 3 * (long)M512);
    wtrans<<<dim3(8, 8, 4), 256, 0, stream>>>(afcW, WfT, 512, 512, M512);
    wtrans<<<dim3(8, 8, 2), 256, 0, stream>>>(fW1,  W1T, 512, 512, M512);
    wtrans<<<dim3(8, 8, 2), 256, 0, stream>>>(fW2,  W2T, 512, 512, M512);
    wconv<<<dim3(4096, 3), 256, 0, stream>>>(conv_W, WCt);

    // ---- bottleneck
    gemmB(x_enc, WdownT, down_b, nullptr, Y, BB*1024, 512, 512, 0, 0, 0, 0, 0);
    gemmB(Y,  WCt,             conv_b + 0,    nullptr, C1, BB*256, 512, 2048, 1, 0, 0, 0, 0);
    gemmB(C1, WCt + 1048576,   conv_b + 512,  nullptr, C2, BB*64,  512, 2048, 1, 0, 0, 0, 0);
    gemmB(C2, WCt + 2*1048576, conv_b + 1024, nullptr, C3, BB*16,  512, 2048, 1, 0, 0, 0, 0);
    pcat_copy<<<(BB*336*512)/256, 256, 0, stream>>>(C1, C2, C3, PCAT);
    gemmB(PCAT, WupT, up_b, nullptr, TMP, BB*336, 512, 512, 0, 0, 336, LT, 1024);
    xenc_copy<<<(BB*1024*512)/256, 256, 0, stream>>>(x_enc, TMP);
    ln_kernel<<<(BB*LT)/4, 256, 0, stream>>>(TMP, bc_g, bc_b, X, 1e-5f);

    // ---- transformer layers
    for (int l = 0; l < 2; l++){
        hipMemsetAsync(SM, 0, (size_t)BB * LT * LT, stream);
        rownorm_kernel<<<(BB*LT)/4, 256, 0, stream>>>(X, XN);
        sim_mfma<<<dim3(274, BB), 256, 0, stream>>>(XN, SIMB);
        topk_sel<<<BB*LT, 256, 0, stream>>>(SIMB, SM);

        for (int j = 0; j < 2; j++){
            int li = l * 2 + j;
            const float* bf = afcb + (size_t)li * 512;
            const float* lg = alng + (size_t)li * 512;
            const float* lb = alnb + (size_t)li * 512;
            // fused QKV projection: writes Q->QbH, K->KbH, V^T->VtH
            gemmB(X, Wqkv + (size_t)li * 3 * M512, nullptr, nullptr, QbH,
                  BB*LT, 1536, 512, 0, 3, 0, 0, 0);
            if (j == 0)
                attn_sparse<<<(BB*NHH*LT)/4, 256, 0, stream>>>(QbH, KbH, VtH, TIDX, TCNT, AO);
            else
                flash_mfma<<<dim3(22, 32), 256, 0, stream>>>(QbH, KbH, VtH, SM, AO);
            gemmB(AO, WfT + (size_t)li * M512, bf, X, TMP, BB*LT, 512, 512, 0, 0, 0, 0, 0);
            ln_kernel<<<(BB*LT)/4, 256, 0, stream>>>(TMP, lg, lb, (j == 0) ? TO : SO, 1e-6f);
        }
        add3_kernel<<<(int)(NBL/256), 256, 0, stream>>>(TO, SO, X);

        // FFN
        gemmB(X,  W1T + (size_t)l * M512, fb1 + (size_t)l*512, nullptr, Hf, BB*LT, 512, 512, 2, 0, 0, 0, 0);
        gemmB(Hf, W2T + (size_t)l * M512, fb2 + (size_t)l*512, X, TMP, BB*LT, 512, 512, 0, 0, 0, 0, 0);
        ln_kernel<<<(BB*LT)/4, 256, 0, stream>>>(TMP, flng + (size_t)l*512, flnb + (size_t)l*512,
                                                 (l == 1) ? (float*)d_out : X, 1e-6f);
    }
}

// Round 7
// 1161.407 us; speedup vs baseline: 3.9686x; 1.1102x over previous
//
#include <hip/hip_runtime.h>
#include <float.h>
#include <math.h>
#include <stdint.h>

#define LT 1360
#define BB 4
#define DM 512
#define NHH 8
#define NBLE 2785280   // BB*LT*512 elements

typedef __attribute__((ext_vector_type(8))) short short8;
typedef __attribute__((ext_vector_type(4))) float f32x4;

__device__ __forceinline__ ushort f2b(float x){
    uint32_t u = __float_as_uint(x);
    return (ushort)((u + 0x7fffu + ((u >> 16) & 1u)) >> 16);
}
__device__ __forceinline__ float b2f(ushort u){
    return __uint_as_float(((uint32_t)u) << 16);
}

// semantic sim buffer layout (per batch)
#define SG0 0
#define SG1 1048576
#define SG2 (SG1 + 65536)
#define SG3 (SG2 + 4096)
#define SBT (SG3 + 256)

__device__ __forceinline__ void blk_info(int i, int& bi, int& st, int& n){
    if (i < 1024){ bi = 0; st = 0;    n = 1024; }
    else if (i < 1280){ bi = 1; st = 1024; n = 256; }
    else if (i < 1344){ bi = 2; st = 1280; n = 64; }
    else { bi = 3; st = 1344; n = 16; }
}

// ---------------- temporal allowed-index lists
__global__ __launch_bounds__(256)
void build_tidx(int* __restrict__ idx, int* __restrict__ cnt){
    int i = blockIdx.x * 256 + threadIdx.x;
    if (i >= LT) return;
    int bi, st, n; blk_info(i, bi, st, n);
    int c = 0; int* row = idx + i * 12;
    int lo = (i - 2 > st) ? i - 2 : st;
    int hi = (i + 2 < st + n - 1) ? i + 2 : st + n - 1;
    for (int j = lo; j <= hi; j++) row[c++] = j;
    if (bi < 3) row[c++] = st + n + (i - st) / 4;
    if (bi > 0){
        int stc = st - n * 4;
        int base = stc + (i - st) * 4;
        for (int t = 0; t < 4; t++) row[c++] = base + t;
    }
    cnt[i] = c;
}

// ---------------- weight transpose+cast: Wd[n*K+k] = bf16(Ws[k*N+n]); dst stride per matrix
__global__ __launch_bounds__(256)
void wtrans(const float* __restrict__ W, ushort* __restrict__ Wt, int K, int N, long dstStride){
    int mat = blockIdx.z;
    const float* Ws = W + (size_t)mat * K * N;
    ushort* Wd = Wt + (size_t)mat * dstStride;
    int k0 = blockIdx.y << 6, n0 = blockIdx.x << 6;
    __shared__ ushort t[64][72];
    int tid = threadIdx.x;
    #pragma unroll
    for (int p = 0; p < 4; p++){
        int idx = tid + (p << 8);
        int r = idx >> 4, c4 = (idx & 15) << 2;
        float4 v = *(const float4*)(Ws + (size_t)(k0 + r) * N + n0 + c4);
        t[c4+0][r] = f2b(v.x); t[c4+1][r] = f2b(v.y);
        t[c4+2][r] = f2b(v.z); t[c4+3][r] = f2b(v.w);
    }
    __syncthreads();
    #pragma unroll
    for (int p = 0; p < 4; p++){
        int idx = tid + (p << 8);
        int r = idx >> 4, c4 = (idx & 15) << 2;
        *(uint2*)&Wd[(size_t)(n0 + r) * K + k0 + c4] = *(uint2*)&t[r][c4];
    }
}

// ---------------- conv weight repack+cast
__global__ __launch_bounds__(256)
void wconv(const float* __restrict__ cw, ushort* __restrict__ wt){
    int conv = blockIdx.y;
    const float* src = cw + (size_t)conv * 512 * 512 * 4;
    ushort* dst = wt + (size_t)conv * 2048 * 512;
    int idx = blockIdx.x * 256 + threadIdx.x;
    int o = idx >> 11, rest = idx & 2047;
    int k = rest >> 9, ii = rest & 511;
    dst[idx] = f2b(src[((size_t)(o << 9) + ii) * 4 + k]);
}

// ---------------- bf16 MFMA GEMM, 64x64 tile, BK=32, 256 thr / 4 waves
// act: 0 none, 1 ELU(cscale*v), 2 relu
// omode: 0 f32 out (+row remap), 1 bf16 out, 2 bf16 V^T out, 3 fused QKV out (N=1536)
__global__ __launch_bounds__(256)
void gemm_bf16(const float* __restrict__ A, const ushort* __restrict__ Bw,
               const float* __restrict__ bias, const float* __restrict__ Rres,
               void* __restrict__ Cout, int M, int N, int K,
               int act, int omode, int mpb, int orpb, int ooff)
{
    __shared__ ushort As[64][40];
    __shared__ ushort Bs[64][40];
    int tid = threadIdx.x;
    int lane = tid & 63, w = tid >> 6, quad = lane >> 4, l15 = lane & 15;
    int gm = blockIdx.y << 6, gn = blockIdx.x << 6;
    int wr = (w >> 1) << 5, wc = (w & 1) << 5;
    int srow = tid >> 2, sc8 = (tid & 3) << 3;
    f32x4 acc[2][2] = {{{0.f,0.f,0.f,0.f},{0.f,0.f,0.f,0.f}},{{0.f,0.f,0.f,0.f},{0.f,0.f,0.f,0.f}}};
    const float* Arow = A + (size_t)(gm + srow) * K;
    const ushort* Brow = Bw + (size_t)(gn + srow) * K;
    for (int k0 = 0; k0 < K; k0 += 32){
        float4 a0 = *(const float4*)(Arow + k0 + sc8);
        float4 a1 = *(const float4*)(Arow + k0 + sc8 + 4);
        uint4 av;
        av.x = (uint32_t)f2b(a0.x) | ((uint32_t)f2b(a0.y) << 16);
        av.y = (uint32_t)f2b(a0.z) | ((uint32_t)f2b(a0.w) << 16);
        av.z = (uint32_t)f2b(a1.x) | ((uint32_t)f2b(a1.y) << 16);
        av.w = (uint32_t)f2b(a1.z) | ((uint32_t)f2b(a1.w) << 16);
        *(uint4*)&As[srow][sc8] = av;
        *(uint4*)&Bs[srow][sc8] = *(const uint4*)(Brow + k0 + sc8);
        __syncthreads();
        short8 af0 = *(const short8*)&As[wr + l15][quad << 3];
        short8 af1 = *(const short8*)&As[wr + 16 + l15][quad << 3];
        short8 bf0 = *(const short8*)&Bs[wc + l15][quad << 3];
        short8 bf1 = *(const short8*)&Bs[wc + 16 + l15][quad << 3];
        acc[0][0] = __builtin_amdgcn_mfma_f32_16x16x32_bf16(af0, bf0, acc[0][0], 0, 0, 0);
        acc[0][1] = __builtin_amdgcn_mfma_f32_16x16x32_bf16(af0, bf1, acc[0][1], 0, 0, 0);
        acc[1][0] = __builtin_amdgcn_mfma_f32_16x16x32_bf16(af1, bf0, acc[1][0], 0, 0, 0);
        acc[1][1] = __builtin_amdgcn_mfma_f32_16x16x32_bf16(af1, bf1, acc[1][1], 0, 0, 0);
        __syncthreads();
    }
    const float cscale = 0.9999950000375f;
    #pragma unroll
    for (int mi = 0; mi < 2; mi++){
        #pragma unroll
        for (int r = 0; r < 4; r++){
            int row = gm + wr + (mi << 4) + (quad << 2) + r;
            #pragma unroll
            for (int ni = 0; ni < 2; ni++){
                int col = gn + wc + (ni << 4) + l15;
                float v = acc[mi][ni][r];
                if (bias) v += bias[col];
                if (Rres) v += Rres[(size_t)row * N + col];
                if (act == 1){ v *= cscale; v = (v > 0.f) ? v : expm1f(v); }
                else if (act == 2){ v = fmaxf(v, 0.f); }
                if (omode == 0){
                    int orow = mpb ? (row / mpb) * orpb + ooff + (row % mpb) : row;
                    ((float*)Cout)[(size_t)orow * N + col] = v;
                } else if (omode == 1){
                    ((ushort*)Cout)[(size_t)row * N + col] = f2b(v);
                } else if (omode == 2){
                    int bb = row / LT, ii = row - bb * LT;
                    ((ushort*)Cout)[((size_t)(bb * 512 + col)) * LT + ii] = f2b(v);
                } else {
                    int seg = col >> 9, c5 = col & 511;
                    ushort* Ob = (ushort*)Cout;
                    if (seg == 0)      Ob[(size_t)row * 512 + c5] = f2b(v);
                    else if (seg == 1) Ob[(size_t)2*NBLE + (size_t)row * 512 + c5] = f2b(v);
                    else {
                        int bb = row / LT, ii = row - bb * LT;
                        Ob[(size_t)4*NBLE + ((size_t)(bb * 512 + c5)) * LT + ii] = f2b(v);
                    }
                }
            }
        }
    }
}

// ---------------- semantic sim via split-bf16 MFMA: sim = hi·hi^T + hi·lo^T + lo·hi^T
__global__ __launch_bounds__(256)
void sim_mfma(const float* __restrict__ XN, float* __restrict__ SIM){
    __shared__ ushort Ah[64][40], Al[64][40], Bh[64][40], Bl[64][40];
    int x = blockIdx.x, b = blockIdx.y;
    int ti, tj, st, n, goff;
    if (x < 256){ ti = x >> 4; tj = x & 15; st = 0; n = 1024; goff = SG0; }
    else if (x < 272){ int y = x - 256; ti = y >> 2; tj = y & 3; st = 1024; n = 256; goff = SG1; }
    else if (x == 272){ ti = 0; tj = 0; st = 1280; n = 64; goff = SG2; }
    else { ti = 0; tj = 0; st = 1344; n = 16; goff = SG3; }
    const float* Xb = XN + (((size_t)b * LT + st) << 9);
    float* Cb = SIM + (size_t)b * SBT + goff;
    int gm = ti << 6, gn = tj << 6;
    int tid = threadIdx.x;
    int lane = tid & 63, w = tid >> 6, quad = lane >> 4, l15 = lane & 15;
    int wr = (w >> 1) << 5, wc = (w & 1) << 5;
    int srow = tid >> 2, sc8 = (tid & 3) << 3;
    int ra = gm + srow; if (ra > n - 1) ra = n - 1;
    int rb = gn + srow; if (rb > n - 1) rb = n - 1;
    f32x4 acc[2][2] = {{{0.f,0.f,0.f,0.f},{0.f,0.f,0.f,0.f}},{{0.f,0.f,0.f,0.f},{0.f,0.f,0.f,0.f}}};
    for (int k0 = 0; k0 < 512; k0 += 32){
        float av8[8], bv8[8];
        *(float4*)&av8[0] = *(const float4*)(Xb + ((size_t)ra << 9) + k0 + sc8);
        *(float4*)&av8[4] = *(const float4*)(Xb + ((size_t)ra << 9) + k0 + sc8 + 4);
        *(float4*)&bv8[0] = *(const float4*)(Xb + ((size_t)rb << 9) + k0 + sc8);
        *(float4*)&bv8[4] = *(const float4*)(Xb + ((size_t)rb << 9) + k0 + sc8 + 4);
        ushort ah[8], al[8], bh[8], bl[8];
        #pragma unroll
        for (int t = 0; t < 8; t++){
            ah[t] = f2b(av8[t]); al[t] = f2b(av8[t] - b2f(ah[t]));
            bh[t] = f2b(bv8[t]); bl[t] = f2b(bv8[t] - b2f(bh[t]));
        }
        uint4 u;
        u.x = (uint32_t)ah[0]|((uint32_t)ah[1]<<16); u.y = (uint32_t)ah[2]|((uint32_t)ah[3]<<16);
        u.z = (uint32_t)ah[4]|((uint32_t)ah[5]<<16); u.w = (uint32_t)ah[6]|((uint32_t)ah[7]<<16);
        *(uint4*)&Ah[srow][sc8] = u;
        u.x = (uint32_t)al[0]|((uint32_t)al[1]<<16); u.y = (uint32_t)al[2]|((uint32_t)al[3]<<16);
        u.z = (uint32_t)al[4]|((uint32_t)al[5]<<16); u.w = (uint32_t)al[6]|((uint32_t)al[7]<<16);
        *(uint4*)&Al[srow][sc8] = u;
        u.x = (uint32_t)bh[0]|((uint32_t)bh[1]<<16); u.y = (uint32_t)bh[2]|((uint32_t)bh[3]<<16);
        u.z = (uint32_t)bh[4]|((uint32_t)bh[5]<<16); u.w = (uint32_t)bh[6]|((uint32_t)bh[7]<<16);
        *(uint4*)&Bh[srow][sc8] = u;
        u.x = (uint32_t)bl[0]|((uint32_t)bl[1]<<16); u.y = (uint32_t)bl[2]|((uint32_t)bl[3]<<16);
        u.z = (uint32_t)bl[4]|((uint32_t)bl[5]<<16); u.w = (uint32_t)bl[6]|((uint32_t)bl[7]<<16);
        *(uint4*)&Bl[srow][sc8] = u;
        __syncthreads();
        short8 ah0 = *(const short8*)&Ah[wr + l15][quad << 3];
        short8 ah1 = *(const short8*)&Ah[wr + 16 + l15][quad << 3];
        short8 al0 = *(const short8*)&Al[wr + l15][quad << 3];
        short8 al1 = *(const short8*)&Al[wr + 16 + l15][quad << 3];
        short8 bh0 = *(const short8*)&Bh[wc + l15][quad << 3];
        short8 bh1 = *(const short8*)&Bh[wc + 16 + l15][quad << 3];
        short8 bl0 = *(const short8*)&Bl[wc + l15][quad << 3];
        short8 bl1 = *(const short8*)&Bl[wc + 16 + l15][quad << 3];
        acc[0][0] = __builtin_amdgcn_mfma_f32_16x16x32_bf16(ah0, bh0, acc[0][0], 0, 0, 0);
        acc[0][0] = __builtin_amdgcn_mfma_f32_16x16x32_bf16(ah0, bl0, acc[0][0], 0, 0, 0);
        acc[0][0] = __builtin_amdgcn_mfma_f32_16x16x32_bf16(al0, bh0, acc[0][0], 0, 0, 0);
        acc[0][1] = __builtin_amdgcn_mfma_f32_16x16x32_bf16(ah0, bh1, acc[0][1], 0, 0, 0);
        acc[0][1] = __builtin_amdgcn_mfma_f32_16x16x32_bf16(ah0, bl1, acc[0][1], 0, 0, 0);
        acc[0][1] = __builtin_amdgcn_mfma_f32_16x16x32_bf16(al0, bh1, acc[0][1], 0, 0, 0);
        acc[1][0] = __builtin_amdgcn_mfma_f32_16x16x32_bf16(ah1, bh0, acc[1][0], 0, 0, 0);
        acc[1][0] = __builtin_amdgcn_mfma_f32_16x16x32_bf16(ah1, bl0, acc[1][0], 0, 0, 0);
        acc[1][0] = __builtin_amdgcn_mfma_f32_16x16x32_bf16(al1, bh0, acc[1][0], 0, 0, 0);
        acc[1][1] = __builtin_amdgcn_mfma_f32_16x16x32_bf16(ah1, bh1, acc[1][1], 0, 0, 0);
        acc[1][1] = __builtin_amdgcn_mfma_f32_16x16x32_bf16(ah1, bl1, acc[1][1], 0, 0, 0);
        acc[1][1] = __builtin_amdgcn_mfma_f32_16x16x32_bf16(al1, bh1, acc[1][1], 0, 0, 0);
        __syncthreads();
    }
    #pragma unroll
    for (int mi = 0; mi < 2; mi++){
        #pragma unroll
        for (int r = 0; r < 4; r++){
            int row = gm + wr + (mi << 4) + (quad << 2) + r;
            if (row < n){
                #pragma unroll
                for (int ni = 0; ni < 2; ni++){
                    int col = gn + wc + (ni << 4) + l15;
                    if (col < n) Cb[(size_t)row * n + col] = acc[mi][ni][r];
                }
            }
        }
    }
}

// ---------------- concat conv pyramids
__global__ __launch_bounds__(256)
void pcat_copy(const float* __restrict__ C1, const float* __restrict__ C2,
               const float* __restrict__ C3, float* __restrict__ PC){
    int idx = blockIdx.x * 256 + threadIdx.x;
    int d = idx & 511;
    int r = (idx >> 9) % 336;
    int b = idx / (336 * 512);
    float v;
    if (r < 256)       v = C1[(((size_t)b * 256 + r) << 9) + d];
    else if (r < 320)  v = C2[(((size_t)b * 64 + (r - 256)) << 9) + d];
    else               v = C3[(((size_t)b * 16 + (r - 320)) << 9) + d];
    PC[idx] = v;
}

__global__ __launch_bounds__(256)
void xenc_copy(const float* __restrict__ xe, float* __restrict__ dst){
    int idx = blockIdx.x * 256 + threadIdx.x;
    int d = idx & 511;
    int l = (idx >> 9) & 1023;
    int b = idx >> 19;
    dst[(((size_t)b * LT + l) << 9) + d] = xe[idx];
}

// ---------------- LayerNorm over 512, wave per row
__global__ __launch_bounds__(256)
void ln_kernel(const float* __restrict__ in, const float* __restrict__ g,
               const float* __restrict__ bta, float* __restrict__ out, float eps){
    int wid = threadIdx.x >> 6, lane = threadIdx.x & 63;
    int row = blockIdx.x * 4 + wid;
    const float* p = in + ((size_t)row << 9);
    float vals[8]; float s = 0.f, s2 = 0.f;
    #pragma unroll
    for (int t = 0; t < 8; t++){
        float v = p[lane + t * 64]; vals[t] = v; s += v; s2 += v * v;
    }
    #pragma unroll
    for (int off = 32; off; off >>= 1){
        s  += __shfl_xor(s,  off, 64);
        s2 += __shfl_xor(s2, off, 64);
    }
    float mu = s * (1.f / 512.f);
    float var = s2 * (1.f / 512.f) - mu * mu;
    float r = rsqrtf(var + eps);
    float* q = out + ((size_t)row << 9);
    #pragma unroll
    for (int t = 0; t < 8; t++){
        int c = lane + t * 64;
        q[c] = (vals[t] - mu) * r * g[c] + bta[c];
    }
}

__global__ __launch_bounds__(256)
void rownorm_kernel(const float* __restrict__ in, float* __restrict__ out){
    int wid = threadIdx.x >> 6, lane = threadIdx.x & 63;
    int row = blockIdx.x * 4 + wid;
    const float* p = in + ((size_t)row << 9);
    float vals[8]; float s2 = 0.f;
    #pragma unroll
    for (int t = 0; t < 8; t++){
        float v = p[lane + t * 64]; vals[t] = v; s2 += v * v;
    }
    #pragma unroll
    for (int off = 32; off; off >>= 1) s2 += __shfl_xor(s2, off, 64);
    float inv = 1.f / fmaxf(sqrtf(s2), 1e-8f);
    float* q = out + ((size_t)row << 9);
    #pragma unroll
    for (int t = 0; t < 8; t++) q[lane + t * 64] = vals[t] * inv;
}

// ---------------- top-k: wave-per-row register selection (no LDS, no barriers)
// lane holds elements j = lane + t*64, t < n/64. 32 iterations of butterfly argmax
// with (value desc, index asc) tie-break == lax.top_k semantics.
__global__ __launch_bounds__(256)
void topk_sel(const float* __restrict__ SIM, uint8_t* __restrict__ SM){
    int wid = threadIdx.x >> 6, lane = threadIdx.x & 63;
    int r = blockIdx.x * 4 + wid;        // 0..B*LT-1
    int b = r / LT, i = r % LT;
    int bi, st, n; blk_info(i, bi, st, n);
    uint8_t* mrow = SM + ((size_t)b * LT + i) * LT + st;
    if (n == 16){                         // k = n: every in-block key selected
        if (lane < 16) mrow[lane] = 1;
        return;
    }
    int goff = (bi == 0) ? SG0 : (bi == 1) ? SG1 : SG2;
    const float* srow = SIM + (size_t)b * SBT + goff + (size_t)(i - st) * n;
    int ns = n >> 6;                      // 16, 4, or 1 slots per lane
    float vals[16];
    #pragma unroll
    for (int t = 0; t < 16; t++)
        vals[t] = (t < ns) ? srow[lane + (t << 6)] : -FLT_MAX;
    for (int it = 0; it < 32; it++){
        float bv = vals[0]; int bt = 0;
        #pragma unroll
        for (int t = 1; t < 16; t++)
            if (vals[t] > bv){ bv = vals[t]; bt = t; }   // strict > keeps lowest t on ties
        int bidx = (bt << 6) + lane;
        #pragma unroll
        for (int off = 1; off < 64; off <<= 1){
            float ov = __shfl_xor(bv, off, 64);
            int   oi = __shfl_xor(bidx, off, 64);
            if (ov > bv || (ov == bv && oi < bidx)){ bv = ov; bidx = oi; }
        }
        if ((bidx & 63) == lane){         // winner's owner lane
            mrow[bidx] = 1;
            int bt2 = bidx >> 6;
            #pragma unroll
            for (int t = 0; t < 16; t++) if (t == bt2) vals[t] = -FLT_MAX;
        }
    }
}

// ---------------- sparse temporal attention (bf16 inputs, V transposed)
__global__ __launch_bounds__(256)
void attn_sparse(const ushort* __restrict__ Q, const ushort* __restrict__ Kp,
                 const ushort* __restrict__ Vt, const int* __restrict__ IDX,
                 const int* __restrict__ CNT, float* __restrict__ O){
    int wid = threadIdx.x >> 6, lane = threadIdx.x & 63;
    int row = blockIdx.x * 4 + wid;
    int b = row / (NHH * LT);
    int rem = row % (NHH * LT);
    int h = rem / LT, i = rem % LT;
    int c = CNT[i];
    int jl = IDX[i * 12 + (lane % 12)];
    float qd = b2f(Q[(((size_t)b * LT + i) << 9) + h * 64 + lane]);
    const ushort* kb = Kp + (((size_t)b * LT) << 9) + h * 64 + lane;
    const ushort* vb = Vt + ((size_t)(b * 512 + h * 64 + lane)) * LT;
    float m = -FLT_MAX, lsum = 0.f, o = 0.f;
    for (int t = 0; t < c; t++){
        int j = __shfl(jl, t, 64);
        float s = qd * b2f(kb[(size_t)j << 9]);
        #pragma unroll
        for (int off = 32; off; off >>= 1) s += __shfl_xor(s, off, 64);
        s *= 0.125f;
        float mn = fmaxf(m, s);
        float sc = __expf(m - mn);
        float p  = __expf(s - mn);
        lsum = lsum * sc + p;
        o = o * sc + p * b2f(vb[j]);
        m = mn;
    }
    O[(((size_t)b * LT + i) << 9) + h * 64 + lane] = o / lsum;
}

// ---------------- MFMA flash attention (semantic, byte mask)
__global__ __launch_bounds__(256)
void flash_mfma(const ushort* __restrict__ Q, const ushort* __restrict__ Kp,
                const ushort* __restrict__ Vt, const uint8_t* __restrict__ Mk,
                float* __restrict__ O)
{
    __shared__ ushort Ks[64][72];
    __shared__ ushort Vs[64][72];
    __shared__ uint8_t Ms[64][64];
    __shared__ ushort Ps[4][16][72];
    int bh = blockIdx.y, b = bh >> 3, h = bh & 7;
    int q0 = blockIdx.x << 6;
    int tid = threadIdx.x;
    int w = tid >> 6, lane = tid & 63, quad = lane >> 4, l15 = lane & 15;

    int qm = q0 + w * 16 + l15;
    int qmc = (qm < LT) ? qm : (LT - 1);
    const ushort* qp = Q + ((size_t)(b * LT + qmc) << 9) + h * 64 + (quad << 3);
    short8 qf0 = *(const short8*)qp;
    short8 qf1 = *(const short8*)(qp + 32);

    float m_i[4] = {-FLT_MAX, -FLT_MAX, -FLT_MAX, -FLT_MAX};
    float l_i[4] = {0.f, 0.f, 0.f, 0.f};
    f32x4 Oacc[4] = {{0.f,0.f,0.f,0.f},{0.f,0.f,0.f,0.f},{0.f,0.f,0.f,0.f},{0.f,0.f,0.f,0.f}};

    int srow = tid >> 2, sc = (tid & 3) << 4;
    const uint8_t* Mbase = Mk + (size_t)b * LT * LT;

    for (int kt = 0; kt < 22; kt++){
        int k0 = kt << 6;
        __syncthreads();
        {
            int krow = k0 + srow; if (krow >= LT) krow = LT - 1;
            const ushort* kp = Kp + ((size_t)(b * LT + krow) << 9) + h * 64 + sc;
            *(uint4*)&Ks[srow][sc]     = *(const uint4*)kp;
            *(uint4*)&Ks[srow][sc + 8] = *(const uint4*)(kp + 8);
            int kbase = k0 + sc; if (kbase > LT - 16) kbase = LT - 16;
            const ushort* vp = Vt + ((size_t)(b * 512 + h * 64 + srow)) * LT + kbase;
            *(uint4*)&Vs[srow][sc]     = *(const uint4*)vp;
            *(uint4*)&Vs[srow][sc + 8] = *(const uint4*)(vp + 8);
            int mrow = q0 + srow; if (mrow >= LT) mrow = LT - 1;
            *(uint4*)&Ms[srow][sc] = *(const uint4*)(Mbase + (size_t)mrow * LT + k0 + sc);
        }
        __syncthreads();
        f32x4 s[4] = {{0.f,0.f,0.f,0.f},{0.f,0.f,0.f,0.f},{0.f,0.f,0.f,0.f},{0.f,0.f,0.f,0.f}};
        #pragma unroll
        for (int nt = 0; nt < 4; nt++){
            short8 kf0 = *(const short8*)&Ks[(nt << 4) + l15][quad << 3];
            short8 kf1 = *(const short8*)&Ks[(nt << 4) + l15][32 + (quad << 3)];
            s[nt] = __builtin_amdgcn_mfma_f32_16x16x32_bf16(qf0, kf0, s[nt], 0, 0, 0);
            s[nt] = __builtin_amdgcn_mfma_f32_16x16x32_bf16(qf1, kf1, s[nt], 0, 0, 0);
        }
        float alpha[4];
        #pragma unroll
        for (int r = 0; r < 4; r++){
            int lrow = (w << 4) + (quad << 2) + r;
            float sv[4]; bool bad[4];
            #pragma unroll
            for (int nt = 0; nt < 4; nt++){
                int kcol = k0 + (nt << 4) + l15;
                uint32_t mw = *(const uint32_t*)&Ms[lrow][(nt << 4) + (l15 & ~3)];
                uint8_t mb = (uint8_t)(mw >> ((l15 & 3) << 3));
                bad[nt] = (mb != 0) || (kcol >= LT);
                sv[nt] = s[nt][r] * 0.125f;
            }
            float tmax = -FLT_MAX;
            #pragma unroll
            for (int nt = 0; nt < 4; nt++) if (!bad[nt]) tmax = fmaxf(tmax, sv[nt]);
            #pragma unroll
            for (int off = 1; off < 16; off <<= 1) tmax = fmaxf(tmax, __shfl_xor(tmax, off, 64));
            float mn = fmaxf(m_i[r], tmax);
            alpha[r] = __expf(m_i[r] - mn);
            float psum = 0.f;
            float pv[4];
            #pragma unroll
            for (int nt = 0; nt < 4; nt++){
                pv[nt] = bad[nt] ? 0.f : __expf(sv[nt] - mn);
                psum += pv[nt];
            }
            #pragma unroll
            for (int off = 1; off < 16; off <<= 1) psum += __shfl_xor(psum, off, 64);
            l_i[r] = l_i[r] * alpha[r] + psum;
            m_i[r] = mn;
            #pragma unroll
            for (int nt = 0; nt < 4; nt++)
                Ps[w][(quad << 2) + r][(nt << 4) + l15] = f2b(pv[nt]);
        }
        #pragma unroll
        for (int dt = 0; dt < 4; dt++)
            #pragma unroll
            for (int r = 0; r < 4; r++)
                Oacc[dt][r] *= alpha[r];
        short8 pf0 = *(const short8*)&Ps[w][l15][quad << 3];
        short8 pf1 = *(const short8*)&Ps[w][l15][32 + (quad << 3)];
        #pragma unroll
        for (int dt = 0; dt < 4; dt++){
            short8 vf0 = *(const short8*)&Vs[(dt << 4) + l15][quad << 3];
            short8 vf1 = *(const short8*)&Vs[(dt << 4) + l15][32 + (quad << 3)];
            Oacc[dt] = __builtin_amdgcn_mfma_f32_16x16x32_bf16(pf0, vf0, Oacc[dt], 0, 0, 0);
            Oacc[dt] = __builtin_amdgcn_mfma_f32_16x16x32_bf16(pf1, vf1, Oacc[dt], 0, 0, 0);
        }
    }
    #pragma unroll
    for (int r = 0; r < 4; r++){
        int qrow = q0 + (w << 4) + (quad << 2) + r;
        if (qrow < LT){
            float inv = 1.f / l_i[r];
            #pragma unroll
            for (int dt = 0; dt < 4; dt++)
                O[((size_t)(b * LT + qrow) << 9) + h * 64 + (dt << 4) + l15] = Oacc[dt][r] * inv;
        }
    }
}

// ---------------- x = (t + s + x)/3
__global__ __launch_bounds__(256)
void add3_kernel(const float* __restrict__ T, const float* __restrict__ S,
                 float* __restrict__ X){
    size_t idx = (size_t)blockIdx.x * 256 + threadIdx.x;
    X[idx] = (T[idx] + S[idx] + X[idx]) * (1.f / 3.f);
}

extern "C" void kernel_launch(void* const* d_in, const int* in_sizes, int n_in,
                              void* d_out, int out_size, void* d_ws, size_t ws_size,
                              hipStream_t stream)
{
    const float* x_enc   = (const float*)d_in[0];
    const float* down_W  = (const float*)d_in[1];
    const float* down_b  = (const float*)d_in[2];
    const float* conv_W  = (const float*)d_in[3];
    const float* conv_b  = (const float*)d_in[4];
    const float* up_W    = (const float*)d_in[5];
    const float* up_b    = (const float*)d_in[6];
    const float* bc_g    = (const float*)d_in[7];
    const float* bc_b    = (const float*)d_in[8];
    const float* aWq     = (const float*)d_in[9];
    const float* aWk     = (const float*)d_in[10];
    const float* aWv     = (const float*)d_in[11];
    const float* afcW    = (const float*)d_in[12];
    const float* afcb    = (const float*)d_in[13];
    const float* alng    = (const float*)d_in[14];
    const float* alnb    = (const float*)d_in[15];
    const float* fW1     = (const float*)d_in[16];
    const float* fb1     = (const float*)d_in[17];
    const float* fW2     = (const float*)d_in[18];
    const float* fb2     = (const float*)d_in[19];
    const float* flng    = (const float*)d_in[20];
    const float* flnb    = (const float*)d_in[21];

    const size_t NBL = (size_t)NBLE;
    float* X   = (float*)d_ws;
    float* TMP = X   + NBL;
    float* Qb  = TMP + NBL;
    float* Kb  = Qb  + NBL;
    float* Vb  = Kb  + NBL;
    float* AO  = Vb  + NBL;
    float* TO  = AO  + NBL;
    float* SO  = TO  + NBL;
    uint8_t* SM = (uint8_t*)(SO + NBL);
    int* TIDX = (int*)(SM + (size_t)BB * LT * LT);
    int* TCNT = TIDX + (size_t)LT * 12;
    ushort* WG = (ushort*)(TCNT + LT);
    const size_t M512 = 262144;
    ushort* WdownT = WG;                 size_t wo = M512;
    ushort* WupT   = WG + wo;            wo += M512;
    ushort* Wqkv   = WG + wo;            wo += 12 * M512;   // 4 layers x [Wq|Wk|Wv]^T
    ushort* WfT    = WG + wo;            wo += 4 * M512;
    ushort* W1T    = WG + wo;            wo += 2 * M512;
    ushort* W2T    = WG + wo;            wo += 2 * M512;
    ushort* WCt    = WG + wo;            wo += 3 * 1048576;
    size_t need = 8 * NBL * sizeof(float) + (size_t)BB * LT * LT
                + (size_t)LT * 13 * 4 + wo * sizeof(ushort);
    if (ws_size < need) return;

    // aliases (lifetimes disjoint)
    float* Y    = Qb;
    float* C1   = Kb;
    float* C2   = C1 + (size_t)BB*256*512;
    float* C3   = C2 + (size_t)BB*64*512;
    float* PCAT = Vb;
    float* XN   = AO;
    float* SIMB = Qb;
    float* Hf   = Qb;
    ushort* QbH = (ushort*)Qb;
    ushort* KbH = (ushort*)Kb;
    ushort* VtH = (ushort*)Vb;

    auto gemmB = [&](const float* A, const ushort* Bw, const float* bias,
                     const float* res, void* C, int M, int N, int K,
                     int act, int omode, int mpb, int orpb, int ooff){
        dim3 grid(N / 64, M / 64);
        gemm_bf16<<<grid, 256, 0, stream>>>(A, Bw, bias, res, C, M, N, K,
                                            act, omode, mpb, orpb, ooff);
    };

    build_tidx<<<(LT + 255) / 256, 256, 0, stream>>>(TIDX, TCNT);
    wtrans<<<dim3(8, 8, 1), 256, 0, stream>>>(down_W, WdownT, 512, 512, M512);
    wtrans<<<dim3(8, 8, 1), 256, 0, stream>>>(up_W,   WupT,   512, 512, M512);
    wtrans<<<dim3(8, 8, 4), 256, 0, stream>>>(aWq,  Wqkv + 0 * M512, 512, 512, 3 * (long)M512);
    wtrans<<<dim3(8, 8, 4), 256, 0, stream>>>(aWk,  Wqkv + 1 * M512, 512, 512, 3 * (long)M512);
    wtrans<<<dim3(8, 8, 4), 256, 0, stream>>>(aWv,  Wqkv + 2 * M512, 512, 512, 3 * (long)M512);
    wtrans<<<dim3(8, 8, 4), 256, 0, stream>>>(afcW, WfT, 512, 512, M512);
    wtrans<<<dim3(8, 8, 2), 256, 0, stream>>>(fW1,  W1T, 512, 512, M512);
    wtrans<<<dim3(8, 8, 2), 256, 0, stream>>>(fW2,  W2T, 512, 512, M512);
    wconv<<<dim3(4096, 3), 256, 0, stream>>>(conv_W, WCt);

    // ---- bottleneck
    gemmB(x_enc, WdownT, down_b, nullptr, Y, BB*1024, 512, 512, 0, 0, 0, 0, 0);
    gemmB(Y,  WCt,             conv_b + 0,    nullptr, C1, BB*256, 512, 2048, 1, 0, 0, 0, 0);
    gemmB(C1, WCt + 1048576,   conv_b + 512,  nullptr, C2, BB*64,  512, 2048, 1, 0, 0, 0, 0);
    gemmB(C2, WCt + 2*1048576, conv_b + 1024, nullptr, C3, BB*16,  512, 2048, 1, 0, 0, 0, 0);
    pcat_copy<<<(BB*336*512)/256, 256, 0, stream>>>(C1, C2, C3, PCAT);
    gemmB(PCAT, WupT, up_b, nullptr, TMP, BB*336, 512, 512, 0, 0, 336, LT, 1024);
    xenc_copy<<<(BB*1024*512)/256, 256, 0, stream>>>(x_enc, TMP);
    ln_kernel<<<(BB*LT)/4, 256, 0, stream>>>(TMP, bc_g, bc_b, X, 1e-5f);

    // ---- transformer layers
    for (int l = 0; l < 2; l++){
        hipMemsetAsync(SM, 0, (size_t)BB * LT * LT, stream);
        rownorm_kernel<<<(BB*LT)/4, 256, 0, stream>>>(X, XN);
        sim_mfma<<<dim3(274, BB), 256, 0, stream>>>(XN, SIMB);
        topk_sel<<<(BB*LT)/4, 256, 0, stream>>>(SIMB, SM);

        for (int j = 0; j < 2; j++){
            int li = l * 2 + j;
            const float* bf = afcb + (size_t)li * 512;
            const float* lg = alng + (size_t)li * 512;
            const float* lb = alnb + (size_t)li * 512;
            // fused QKV projection: writes Q->QbH, K->KbH, V^T->VtH
            gemmB(X, Wqkv + (size_t)li * 3 * M512, nullptr, nullptr, QbH,
                  BB*LT, 1536, 512, 0, 3, 0, 0, 0);
            if (j == 0)
                attn_sparse<<<(BB*NHH*LT)/4, 256, 0, stream>>>(QbH, KbH, VtH, TIDX, TCNT, AO);
            else
                flash_mfma<<<dim3(22, 32), 256, 0, stream>>>(QbH, KbH, VtH, SM, AO);
            gemmB(AO, WfT + (size_t)li * M512, bf, X, TMP, BB*LT, 512, 512, 0, 0, 0, 0, 0);
            ln_kernel<<<(BB*LT)/4, 256, 0, stream>>>(TMP, lg, lb, (j == 0) ? TO : SO, 1e-6f);
        }
        add3_kernel<<<(int)(NBL/256), 256, 0, stream>>>(TO, SO, X);

        // FFN
        gemmB(X,  W1T + (size_t)l * M512, fb1 + (size_t)l*512, nullptr, Hf, BB*LT, 512, 512, 2, 0, 0, 0, 0);
        gemmB(Hf, W2T + (size_t)l * M512, fb2 + (size_t)l*512, X, TMP, BB*LT, 512, 512, 0, 0, 0, 0, 0);
        ln_kernel<<<(BB*LT)/4, 256, 0, stream>>>(TMP, flng + (size_t)l*512, flnb + (size_t)l*512,
                                                 (l == 1) ? (float*)d_out : X, 1e-6f);
    }
}